// Round 2
// baseline (17969.339 us; speedup 1.0000x reference)
//
#include <hip/hip_runtime.h>
#include <hip/hip_bf16.h>

// 5-layer GNN encoder x2 branches + projector + mean-pool + L2norm + logits.
// Round 2: bf16 activations (ws ~250MB, fits small workspace), CSR gather
// (no fp32 atomics), fused pool+norm. GEMMs still fp32 vector-ALU.
//
// d_ws layout (bytes):
//   h   bf16 [N,300]   @ 0          (60,000,000)
//   agg bf16 [N,300]   @ 60,000,000 (60,000,000)   (also projector output)
//   hid bf16 [N,600]   @120,000,000 (120,000,000)
//   f0  f32  [4096,300]@240,000,000 (4,915,200)
//   f1  f32  [4096,300]@244,915,200 (4,915,200)    total 249,830,400 B
// d_out doubles as scratch (~3MB: CSR + gstart + BN stats), consumed before
// the final logits GEMM overwrites it.

#define EMB 300
#define EMBC 75      // 300/4 bf16x4 chunks
#define HID 600
#define NGRAPH 4096
#define BN_EPS 1e-5f
#define INV_TEMP 25.0f

typedef __hip_bfloat16 bf16;
struct __align__(8) bf4 { bf16 x, y, z, w; };

__device__ inline float b2f(bf16 v) { return __bfloat162float(v); }
__device__ inline bf16 f2b(float v) { return __float2bfloat16(v); }

// ---------------- small utility kernels ----------------

__global__ void k_zero_f(float* __restrict__ p, int n) {
    int i = blockIdx.x * blockDim.x + threadIdx.x;
    if (i < n) p[i] = 0.f;
}
__global__ void k_zero_i(int* __restrict__ p, int n) {
    int i = blockIdx.x * blockDim.x + threadIdx.x;
    if (i < n) p[i] = 0;
}

// ---------------- CSR build (dst-sorted edge ids) ----------------

__global__ void k_hist(const int* __restrict__ ei, int* __restrict__ deg, int E) {
    int e = blockIdx.x * blockDim.x + threadIdx.x;
    if (e < E) atomicAdd(&deg[ei[E + e]], 1);
}

__global__ void k_chunksum(const int* __restrict__ deg, int* __restrict__ csum, int total) {
    __shared__ int s[256];
    int t = threadIdx.x, i = blockIdx.x * 256 + t;
    s[t] = (i < total) ? deg[i] : 0;
    __syncthreads();
    for (int off = 128; off > 0; off >>= 1) {
        if (t < off) s[t] += s[t + off];
        __syncthreads();
    }
    if (t == 0) csum[blockIdx.x] = s[0];
}

__global__ void k_scanchunks(const int* __restrict__ csum, int* __restrict__ coff, int n) {
    if (threadIdx.x == 0) {
        int acc = 0;
        for (int b = 0; b < n; ++b) { coff[b] = acc; acc += csum[b]; }
    }
}

__global__ void k_scan2(const int* __restrict__ deg, const int* __restrict__ coff,
                        int* __restrict__ rowstart, int total) {
    __shared__ int s[256];
    int t = threadIdx.x, b = blockIdx.x, i = b * 256 + t;
    int v = (i < total) ? deg[i] : 0;
    s[t] = v;
    __syncthreads();
    for (int off = 1; off < 256; off <<= 1) {
        int u = (t >= off) ? s[t - off] : 0;
        __syncthreads();
        s[t] += u;
        __syncthreads();
    }
    if (i < total) rowstart[i] = coff[b] + s[t] - v;  // exclusive prefix
}

__global__ void k_initcursor(const int* __restrict__ rowstart, int* __restrict__ cur, int N) {
    int i = blockIdx.x * blockDim.x + threadIdx.x;
    if (i < N) cur[i] = rowstart[i];
}

__global__ void k_fill(const int* __restrict__ ei, int* __restrict__ cur,
                       int* __restrict__ esorted, int E) {
    int e = blockIdx.x * blockDim.x + threadIdx.x;
    if (e < E) {
        int p = atomicAdd(&cur[ei[E + e]], 1);
        esorted[p] = e;
    }
}

// graph start offsets from the sorted batch array (4097 binary searches)
__global__ void k_gstart(const int* __restrict__ batch, int* __restrict__ gstart, int N) {
    int g = blockIdx.x * blockDim.x + threadIdx.x;
    if (g > NGRAPH) return;
    int lo = 0, hi = N;
    while (lo < hi) { int mid = (lo + hi) >> 1; if (batch[mid] < g) lo = mid + 1; else hi = mid; }
    gstart[g] = lo;
}

// ---------------- node init & aggregation ----------------

__global__ void k_init_h(const int* __restrict__ x,
                         const float4* __restrict__ ae1,
                         const float4* __restrict__ ae2,
                         bf4* __restrict__ h4, int N) {
    int idx = blockIdx.x * blockDim.x + threadIdx.x;
    if (idx >= N * EMBC) return;
    int i = idx / EMBC, j = idx % EMBC;
    int a0 = x[2 * i], a1 = x[2 * i + 1];
    float4 u = ae1[a0 * EMBC + j];
    float4 v = ae2[a1 * EMBC + j];
    bf4 r = { f2b(u.x + v.x), f2b(u.y + v.y), f2b(u.z + v.z), f2b(u.w + v.w) };
    h4[idx] = r;
}

// agg[n] = h[n] + self_emb + sum_{e: dst==n} (h[src(e)] + e1[a0]+e2[a1])
__global__ void k_aggregate(const bf4* __restrict__ h4,
                            const int* __restrict__ ei,
                            const int* __restrict__ ea,
                            const float4* __restrict__ e1,  // [6,75] f4
                            const float4* __restrict__ e2,  // [3,75] f4
                            const int* __restrict__ rowstart,
                            const int* __restrict__ esorted,
                            bf4* __restrict__ agg4, int N, int E) {
    int idx = blockIdx.x * blockDim.x + threadIdx.x;
    if (idx >= N * EMBC) return;
    int n = idx / EMBC, j = idx % EMBC;
    bf4 hv = h4[idx];
    float4 s1 = e1[4 * EMBC + j];  // self-loop edge_attr [4,0]
    float4 s2 = e2[j];
    float ax = b2f(hv.x) + s1.x + s2.x;
    float ay = b2f(hv.y) + s1.y + s2.y;
    float az = b2f(hv.z) + s1.z + s2.z;
    float aw = b2f(hv.w) + s1.w + s2.w;
    int p0 = rowstart[n], p1 = rowstart[n + 1];
    for (int p = p0; p < p1; ++p) {
        int e = esorted[p];
        int s = ei[e];
        int a0 = ea[2 * e], a1 = ea[2 * e + 1];
        bf4 hs = h4[(size_t)s * EMBC + j];
        float4 v1 = e1[a0 * EMBC + j];
        float4 v2 = e2[a1 * EMBC + j];
        ax += b2f(hs.x) + v1.x + v2.x;
        ay += b2f(hs.y) + v1.y + v2.y;
        az += b2f(hs.z) + v1.z + v2.z;
        aw += b2f(hs.w) + v1.w + v2.w;
    }
    bf4 r = { f2b(ax), f2b(ay), f2b(az), f2b(aw) };
    agg4[idx] = r;
}

// ---------------- GEMM: C[M,Nc] = A_bf16[M,K] @ B_f32[K,Nc] + bias ----------------
#define BM 64
#define BN 64
#define BKK 20

__global__ void k_gemm_bf(const bf16* __restrict__ A, const float* __restrict__ B,
                          const float* __restrict__ bias, bf16* __restrict__ C,
                          int M, int Nc, int K, int relu) {
    __shared__ float As[BKK][BM];
    __shared__ float Bs[BKK][BN];
    int tid = threadIdx.x;
    int tx = tid & 15, ty = tid >> 4;
    int row0 = blockIdx.y * BM;
    int col0 = blockIdx.x * BN;
    float acc[4][4] = {};
    for (int k0 = 0; k0 < K; k0 += BKK) {
        for (int t = tid; t < BM * BKK; t += 256) {
            int r = t / BKK, kk = t % BKK;
            int gr = row0 + r, gk = k0 + kk;
            As[kk][r] = (gr < M && gk < K) ? b2f(A[(size_t)gr * K + gk]) : 0.f;
        }
        for (int t = tid; t < BKK * BN; t += 256) {
            int kk = t / BN, c = t % BN;
            int gc = col0 + c, gk = k0 + kk;
            Bs[kk][c] = (gc < Nc && gk < K) ? B[(size_t)gk * Nc + gc] : 0.f;
        }
        __syncthreads();
        #pragma unroll
        for (int kk = 0; kk < BKK; ++kk) {
            float4 a4 = reinterpret_cast<const float4*>(&As[kk][0])[ty];
            float4 b4 = reinterpret_cast<const float4*>(&Bs[kk][0])[tx];
            float a[4] = {a4.x, a4.y, a4.z, a4.w};
            float b[4] = {b4.x, b4.y, b4.z, b4.w};
            #pragma unroll
            for (int i = 0; i < 4; ++i)
                #pragma unroll
                for (int j = 0; j < 4; ++j)
                    acc[i][j] += a[i] * b[j];
        }
        __syncthreads();
    }
    #pragma unroll
    for (int i = 0; i < 4; ++i) {
        int gr = row0 + ty * 4 + i;
        if (gr >= M) continue;
        #pragma unroll
        for (int j = 0; j < 4; ++j) {
            int gc = col0 + tx * 4 + j;
            if (gc >= Nc) continue;
            float v = acc[i][j] + bias[gc];
            if (relu) v = fmaxf(v, 0.f);
            C[(size_t)gr * Nc + gc] = f2b(v);
        }
    }
}

// logits: C[M,Nc] = scale * A_f32[M,K] @ B_f32[Nc,K]^T
__global__ void k_gemm_nt(const float* __restrict__ A, const float* __restrict__ B,
                          float* __restrict__ C, int M, int Nc, int K, float scale) {
    __shared__ float As[BKK][BM];
    __shared__ float Bs[BKK][BN];
    int tid = threadIdx.x;
    int tx = tid & 15, ty = tid >> 4;
    int row0 = blockIdx.y * BM;
    int col0 = blockIdx.x * BN;
    float acc[4][4] = {};
    for (int k0 = 0; k0 < K; k0 += BKK) {
        for (int t = tid; t < BM * BKK; t += 256) {
            int r = t / BKK, kk = t % BKK;
            int gr = row0 + r, gk = k0 + kk;
            As[kk][r] = (gr < M && gk < K) ? A[(size_t)gr * K + gk] : 0.f;
        }
        for (int t = tid; t < BN * BKK; t += 256) {
            int c = t / BKK, kk = t % BKK;
            int gc = col0 + c, gk = k0 + kk;
            Bs[kk][c] = (gc < Nc && gk < K) ? B[(size_t)gc * K + gk] : 0.f;
        }
        __syncthreads();
        #pragma unroll
        for (int kk = 0; kk < BKK; ++kk) {
            float4 a4 = reinterpret_cast<const float4*>(&As[kk][0])[ty];
            float4 b4 = reinterpret_cast<const float4*>(&Bs[kk][0])[tx];
            float a[4] = {a4.x, a4.y, a4.z, a4.w};
            float b[4] = {b4.x, b4.y, b4.z, b4.w};
            #pragma unroll
            for (int i = 0; i < 4; ++i)
                #pragma unroll
                for (int j = 0; j < 4; ++j)
                    acc[i][j] += a[i] * b[j];
        }
        __syncthreads();
    }
    #pragma unroll
    for (int i = 0; i < 4; ++i) {
        int gr = row0 + ty * 4 + i;
        if (gr >= M) continue;
        #pragma unroll
        for (int j = 0; j < 4; ++j) {
            int gc = col0 + tx * 4 + j;
            if (gc >= Nc) continue;
            C[(size_t)gr * Nc + gc] = acc[i][j] * scale;
        }
    }
}

// ---------------- batch norm ----------------

__global__ void k_colstats(const bf16* __restrict__ h, float* __restrict__ stats,
                           int N, int chunk) {
    int c = threadIdx.x;
    if (c >= EMB) return;
    int r0 = blockIdx.x * chunk;
    int r1 = min(N, r0 + chunk);
    float s = 0.f, q = 0.f;
    for (int r = r0; r < r1; ++r) {
        float v = b2f(h[(size_t)r * EMB + c]);
        s += v; q += v * v;
    }
    atomicAdd(&stats[c], s);
    atomicAdd(&stats[EMB + c], q);
}

__global__ void k_bn_prep(float* __restrict__ stats, const float* __restrict__ gamma,
                          const float* __restrict__ beta, float invN) {
    int c = threadIdx.x;
    if (c >= EMB) return;
    float mean = stats[c] * invN;
    float var = stats[EMB + c] * invN - mean * mean;
    float scale = gamma[c] * rsqrtf(var + BN_EPS);
    stats[c] = scale;
    stats[EMB + c] = beta[c] - mean * scale;
}

__global__ void k_bn_apply(bf4* __restrict__ h4, const float* __restrict__ stats,
                           int N, int relu) {
    int idx = blockIdx.x * blockDim.x + threadIdx.x;
    if (idx >= N * EMBC) return;
    int c = (idx % EMBC) * 4;
    bf4 v = h4[idx];
    float a = b2f(v.x) * stats[c + 0] + stats[EMB + c + 0];
    float b = b2f(v.y) * stats[c + 1] + stats[EMB + c + 1];
    float cc = b2f(v.z) * stats[c + 2] + stats[EMB + c + 2];
    float d = b2f(v.w) * stats[c + 3] + stats[EMB + c + 3];
    if (relu) {
        a = fmaxf(a, 0.f); b = fmaxf(b, 0.f);
        cc = fmaxf(cc, 0.f); d = fmaxf(d, 0.f);
    }
    bf4 r = { f2b(a), f2b(b), f2b(cc), f2b(d) };
    h4[idx] = r;
}

// ---------------- fused pool + mean + L2 normalize ----------------
// one block (320 threads = 5 waves) per graph; rows contiguous per sorted batch
__global__ void k_poolnorm(const bf16* __restrict__ proj, const int* __restrict__ gstart,
                           float* __restrict__ f) {
    int g = blockIdx.x, t = threadIdx.x;
    int s = gstart[g], e = gstart[g + 1];
    float sum = 0.f;
    if (t < EMB)
        for (int r = s; r < e; ++r) sum += b2f(proj[(size_t)r * EMB + t]);
    float cnt = fmaxf((float)(e - s), 1.f);
    float m = sum / cnt;
    float q = (t < EMB) ? m * m : 0.f;
    for (int off = 32; off > 0; off >>= 1) q += __shfl_down(q, off, 64);
    __shared__ float red[5];
    int lane = t & 63, wid = t >> 6;
    if (lane == 0) red[wid] = q;
    __syncthreads();
    float tot = red[0] + red[1] + red[2] + red[3] + red[4];
    float invn = 1.f / fmaxf(sqrtf(tot), 1e-12f);
    if (t < EMB) f[(size_t)g * EMB + t] = m * invn;
}

// ---------------- host ----------------

static inline int ceil_div(int a, int b) { return (a + b - 1) / b; }

extern "C" void kernel_launch(void* const* d_in, const int* in_sizes, int n_in,
                              void* d_out, int out_size, void* d_ws, size_t ws_size,
                              hipStream_t stream) {
    const int N = in_sizes[0] / 2;    // 100000
    const int E = in_sizes[1] / 2;    // 400000

    const int* x[2]  = { (const int*)d_in[0], (const int*)d_in[4] };
    const int* ei[2] = { (const int*)d_in[1], (const int*)d_in[5] };
    const int* ea[2] = { (const int*)d_in[2], (const int*)d_in[6] };
    const int* bt[2] = { (const int*)d_in[3], (const int*)d_in[7] };
    const float* atom1 = (const float*)d_in[8];
    const float* atom2 = (const float*)d_in[9];
    const float* ee1 = (const float*)d_in[10];   // [5,6,300]
    const float* ee2 = (const float*)d_in[11];   // [5,3,300]
    const float* w1  = (const float*)d_in[12];   // [5,300,600]
    const float* b1  = (const float*)d_in[13];   // [5,600]
    const float* w2  = (const float*)d_in[14];   // [5,600,300]
    const float* b2  = (const float*)d_in[15];   // [5,300]
    const float* gam = (const float*)d_in[16];
    const float* bet = (const float*)d_in[17];
    const float* pw  = (const float*)d_in[18];   // [300,300]
    const float* pb  = (const float*)d_in[19];
    float* out = (float*)d_out;

    // workspace (bf16 activations)
    char* wsb = (char*)d_ws;
    bf16* h    = (bf16*)(wsb);
    bf16* agg  = (bf16*)(wsb + 60000000);
    bf16* hid  = (bf16*)(wsb + 120000000);
    float* f0  = (float*)(wsb + 240000000);
    float* f1  = (float*)(wsb + 244915200);

    // scratch inside d_out (consumed before final logits GEMM)
    int* deg      = (int*)d_out;              // N+1
    int* rowstart = deg + (N + 1);            // N+1
    int* cursor   = rowstart + (N + 1);       // N
    int* esorted  = cursor + N;               // E
    int* csum     = esorted + E;              // 512
    int* coff     = csum + 512;               // 512
    int* gstart   = coff + 512;               // 4097
    float* stats  = (float*)(gstart + 4097);  // 600

    const int TB = 256;
    const int nh_blocks = ceil_div(N * EMBC, TB);
    const int nchunks = ceil_div(N + 1, 256);       // 391
    const int chunk = ceil_div(N, 256);
    const float invN = 1.f / (float)N;

    dim3 g1(ceil_div(HID, BN), ceil_div(N, BM));
    dim3 g2(ceil_div(EMB, BN), ceil_div(N, BM));
    dim3 gl(ceil_div(NGRAPH, BN), ceil_div(NGRAPH, BM));

    for (int br = 0; br < 2; ++br) {
        float* fout = br == 0 ? f0 : f1;
        // ---- CSR build ----
        k_zero_i<<<ceil_div(N + 1, TB), TB, 0, stream>>>(deg, N + 1);
        k_hist<<<ceil_div(E, TB), TB, 0, stream>>>(ei[br], deg, E);
        k_chunksum<<<nchunks, 256, 0, stream>>>(deg, csum, N + 1);
        k_scanchunks<<<1, 64, 0, stream>>>(csum, coff, nchunks);
        k_scan2<<<nchunks, 256, 0, stream>>>(deg, coff, rowstart, N + 1);
        k_initcursor<<<ceil_div(N, TB), TB, 0, stream>>>(rowstart, cursor, N);
        k_fill<<<ceil_div(E, TB), TB, 0, stream>>>(ei[br], cursor, esorted, E);
        k_gstart<<<ceil_div(NGRAPH + 1, TB), TB, 0, stream>>>(bt[br], gstart, N);
        // ---- encoder ----
        k_init_h<<<nh_blocks, TB, 0, stream>>>(x[br], (const float4*)atom1,
                                               (const float4*)atom2, (bf4*)h, N);
        for (int l = 0; l < 5; ++l) {
            const float* e1 = ee1 + (size_t)l * 6 * EMB;
            const float* e2 = ee2 + (size_t)l * 3 * EMB;
            k_aggregate<<<nh_blocks, TB, 0, stream>>>((const bf4*)h, ei[br], ea[br],
                                                      (const float4*)e1, (const float4*)e2,
                                                      rowstart, esorted, (bf4*)agg, N, E);
            k_gemm_bf<<<g1, 256, 0, stream>>>(agg, w1 + (size_t)l * EMB * HID,
                                              b1 + (size_t)l * HID, hid, N, HID, EMB, 1);
            k_gemm_bf<<<g2, 256, 0, stream>>>(hid, w2 + (size_t)l * HID * EMB,
                                              b2 + (size_t)l * EMB, h, N, EMB, HID, 0);
            k_zero_f<<<ceil_div(2 * EMB, TB), TB, 0, stream>>>(stats, 2 * EMB);
            k_colstats<<<256, 320, 0, stream>>>(h, stats, N, chunk);
            k_bn_prep<<<1, 320, 0, stream>>>(stats, gam + (size_t)l * EMB,
                                             bet + (size_t)l * EMB, invN);
            k_bn_apply<<<nh_blocks, TB, 0, stream>>>((bf4*)h, stats, N, l != 4 ? 1 : 0);
        }
        // projector (output into agg buffer, bf16)
        k_gemm_bf<<<g2, 256, 0, stream>>>(h, pw, pb, agg, N, EMB, EMB, 0);
        // fused pool + mean + L2 norm
        k_poolnorm<<<NGRAPH, 320, 0, stream>>>(agg, gstart, fout);
    }
    // logits = f0 @ f1^T / TEMP  (overwrites the d_out scratch)
    k_gemm_nt<<<gl, 256, 0, stream>>>(f0, f1, out, NGRAPH, NGRAPH, EMB, INV_TEMP);
}

// Round 3
// 8985.056 us; speedup vs baseline: 1.9999x; 1.9999x over previous
//
#include <hip/hip_runtime.h>
#include <hip/hip_bf16.h>

// 5-layer GNN encoder x2 branches + projector + mean-pool + L2norm + logits.
// Round 3: MFMA bf16 GEMMs with split-weight (hi/lo) fp32-equivalent numerics.
// BN-apply fused into next aggregate / projector staging (one fewer bf16
// rounding per layer). CSR gather aggregation (no fp32 atomics).
//
// d_ws layout (bytes), total 253,830,400:
//   h    bf16 [N,300]  @ 0            (60,000,000)  pre-BN layer output
//   agg  bf16 [N,320]  @ 60,000,000   (64,000,000)  K-padded (zeros in 300..319)
//   hid  bf16 [N,600]  @ 124,000,000  (120,000,000)
//   f0   f32  [4096,300] @ 244,000,000 (4,915,200)
//   f1   f32  [4096,300] @ 248,915,200 (4,915,200)
// d_out doubles as scratch (CSR + stats + split weights ~11.4MB), all consumed
// before the final logits GEMM overwrites it.

#define EMB 300
#define EMBC 75       // 300/4 chunks (h pitch 300)
#define AGGP 320      // agg row pitch (elems)
#define AGGC 80       // agg chunks per row
#define HID 600
#define NGRAPH 4096
#define BN_EPS 1e-5f
#define INV_TEMP 25.0f

typedef __hip_bfloat16 bf16;
struct __align__(8) bf4 { bf16 x, y, z, w; };
typedef __attribute__((ext_vector_type(8))) short short8;
typedef __attribute__((ext_vector_type(4))) float float4v;

__device__ inline float b2f(bf16 v) { return __bfloat162float(v); }
__device__ inline bf16 f2b(float v) { return __float2bfloat16(v); }
__device__ inline float u2f(unsigned short u) {
    unsigned x = ((unsigned)u) << 16; float f; __builtin_memcpy(&f, &x, 4); return f;
}
__device__ inline unsigned short f2bu(float f) {
    bf16 b = __float2bfloat16(f); unsigned short u; __builtin_memcpy(&u, &b, 2); return u;
}

// ---------------- small utility ----------------

__global__ void k_zero_f(float* __restrict__ p, int n) {
    int i = blockIdx.x * blockDim.x + threadIdx.x;
    if (i < n) p[i] = 0.f;
}
__global__ void k_zero_i(int* __restrict__ p, int n) {
    int i = blockIdx.x * blockDim.x + threadIdx.x;
    if (i < n) p[i] = 0;
}

// ---------------- weight split: W[K][N] f32 -> Wt_hi/lo[Npad][Kpad] bf16 ----------------

__global__ void k_split(const float* __restrict__ W, int K, int N, int Kpad, int Npad,
                        unsigned short* __restrict__ hi, unsigned short* __restrict__ lo) {
    int idx = blockIdx.x * blockDim.x + threadIdx.x;
    if (idx >= Npad * Kpad) return;
    int n = idx / Kpad, k = idx % Kpad;
    float v = (n < N && k < K) ? W[(size_t)k * N + n] : 0.f;
    bf16 h = __float2bfloat16(v);
    float rem = v - __bfloat162float(h);
    bf16 l = __float2bfloat16(rem);
    unsigned short hu, lu;
    __builtin_memcpy(&hu, &h, 2); __builtin_memcpy(&lu, &l, 2);
    hi[idx] = hu; lo[idx] = lu;
}

// ---------------- CSR build (dst-sorted edge ids) ----------------

__global__ void k_hist(const int* __restrict__ ei, int* __restrict__ deg, int E) {
    int e = blockIdx.x * blockDim.x + threadIdx.x;
    if (e < E) atomicAdd(&deg[ei[E + e]], 1);
}

__global__ void k_chunksum(const int* __restrict__ deg, int* __restrict__ csum, int total) {
    __shared__ int s[256];
    int t = threadIdx.x, i = blockIdx.x * 256 + t;
    s[t] = (i < total) ? deg[i] : 0;
    __syncthreads();
    for (int off = 128; off > 0; off >>= 1) {
        if (t < off) s[t] += s[t + off];
        __syncthreads();
    }
    if (t == 0) csum[blockIdx.x] = s[0];
}

__global__ void k_scanchunks(const int* __restrict__ csum, int* __restrict__ coff, int n) {
    if (threadIdx.x == 0) {
        int acc = 0;
        for (int b = 0; b < n; ++b) { coff[b] = acc; acc += csum[b]; }
    }
}

__global__ void k_scan2(const int* __restrict__ deg, const int* __restrict__ coff,
                        int* __restrict__ rowstart, int total) {
    __shared__ int s[256];
    int t = threadIdx.x, b = blockIdx.x, i = b * 256 + t;
    int v = (i < total) ? deg[i] : 0;
    s[t] = v;
    __syncthreads();
    for (int off = 1; off < 256; off <<= 1) {
        int u = (t >= off) ? s[t - off] : 0;
        __syncthreads();
        s[t] += u;
        __syncthreads();
    }
    if (i < total) rowstart[i] = coff[b] + s[t] - v;
}

__global__ void k_initcursor(const int* __restrict__ rowstart, int* __restrict__ cur, int N) {
    int i = blockIdx.x * blockDim.x + threadIdx.x;
    if (i < N) cur[i] = rowstart[i];
}

__global__ void k_fill(const int* __restrict__ ei, int* __restrict__ cur,
                       int* __restrict__ esorted, int E) {
    int e = blockIdx.x * blockDim.x + threadIdx.x;
    if (e < E) {
        int p = atomicAdd(&cur[ei[E + e]], 1);
        esorted[p] = e;
    }
}

__global__ void k_gstart(const int* __restrict__ batch, int* __restrict__ gstart, int N) {
    int g = blockIdx.x * blockDim.x + threadIdx.x;
    if (g > NGRAPH) return;
    int lo = 0, hi = N;
    while (lo < hi) { int mid = (lo + hi) >> 1; if (batch[mid] < g) lo = mid + 1; else hi = mid; }
    gstart[g] = lo;
}

// ---------------- node init & aggregation (with fused BN affine) ----------------

__global__ void k_init_h(const int* __restrict__ x,
                         const float4* __restrict__ ae1,
                         const float4* __restrict__ ae2,
                         bf4* __restrict__ h4, int N) {
    int idx = blockIdx.x * blockDim.x + threadIdx.x;
    if (idx >= N * EMBC) return;
    int i = idx / EMBC, j = idx % EMBC;
    int a0 = x[2 * i], a1 = x[2 * i + 1];
    float4 u = ae1[a0 * EMBC + j];
    float4 v = ae2[a1 * EMBC + j];
    bf4 r = { f2b(u.x + v.x), f2b(u.y + v.y), f2b(u.z + v.z), f2b(u.w + v.w) };
    h4[idx] = r;
}

// agg[n] = act(h[n]) + self_emb + sum_{e: dst==n} (act(h[src(e)]) + eemb)
// act(x) = relu(scale*x + shift) when use_aff (BN of previous layer), else x.
// agg rows have pitch AGGP=320; chunks 75..79 written zero (K padding for GEMM1).
__global__ void k_aggregate(const bf4* __restrict__ h4,
                            const int* __restrict__ ei,
                            const int* __restrict__ ea,
                            const float4* __restrict__ e1,  // [6,75] f4
                            const float4* __restrict__ e2,  // [3,75] f4
                            const int* __restrict__ rowstart,
                            const int* __restrict__ esorted,
                            const float* __restrict__ stats, int use_aff,
                            bf4* __restrict__ agg4, int N, int E) {
    int idx = blockIdx.x * blockDim.x + threadIdx.x;
    if (idx >= N * AGGC) return;
    int n = idx / AGGC, j = idx % AGGC;
    if (j >= EMBC) {                     // zero K-pad
        bf4 z = { f2b(0.f), f2b(0.f), f2b(0.f), f2b(0.f) };
        agg4[idx] = z;
        return;
    }
    float4 sc = make_float4(1.f, 1.f, 1.f, 1.f);
    float4 sh = make_float4(0.f, 0.f, 0.f, 0.f);
    if (use_aff) {
        sc = ((const float4*)stats)[j];
        sh = ((const float4*)(stats + EMB))[j];
    }
    bf4 hv = h4[(size_t)n * EMBC + j];
    float hx = b2f(hv.x), hy = b2f(hv.y), hz = b2f(hv.z), hw = b2f(hv.w);
    if (use_aff) {
        hx = fmaxf(hx * sc.x + sh.x, 0.f); hy = fmaxf(hy * sc.y + sh.y, 0.f);
        hz = fmaxf(hz * sc.z + sh.z, 0.f); hw = fmaxf(hw * sc.w + sh.w, 0.f);
    }
    float4 s1 = e1[4 * EMBC + j];        // self-loop edge_attr [4,0]
    float4 s2 = e2[j];
    float ax = hx + s1.x + s2.x, ay = hy + s1.y + s2.y;
    float az = hz + s1.z + s2.z, aw = hw + s1.w + s2.w;
    int p0 = rowstart[n], p1 = rowstart[n + 1];
    for (int p = p0; p < p1; ++p) {
        int e = esorted[p];
        int s = ei[e];
        int a0 = ea[2 * e], a1 = ea[2 * e + 1];
        bf4 hs = h4[(size_t)s * EMBC + j];
        float gx = b2f(hs.x), gy = b2f(hs.y), gz = b2f(hs.z), gw = b2f(hs.w);
        if (use_aff) {
            gx = fmaxf(gx * sc.x + sh.x, 0.f); gy = fmaxf(gy * sc.y + sh.y, 0.f);
            gz = fmaxf(gz * sc.z + sh.z, 0.f); gw = fmaxf(gw * sc.w + sh.w, 0.f);
        }
        float4 v1 = e1[a0 * EMBC + j];
        float4 v2 = e2[a1 * EMBC + j];
        ax += gx + v1.x + v2.x; ay += gy + v1.y + v2.y;
        az += gz + v1.z + v2.z; aw += gw + v1.w + v2.w;
    }
    bf4 r = { f2b(ax), f2b(ay), f2b(az), f2b(aw) };
    agg4[idx] = r;
}

// ---------------- MFMA GEMM: C_bf16[M,Nc] = A_bf16[M,K] @ (Bhi+Blo)^T + bias ----------------
// B stored transposed+padded: [Npad][Kpad] bf16, ldb=Kpad. Two MFMA passes
// (hi, lo) into one fp32 acc == bf16-act x fp32-weight numerics.
// Tile 128x64x64; 4 waves, each 32 rows x 64 cols of C.

#define GBM 128
#define GBN 64
#define GBK 64

__global__ __launch_bounds__(256)
void k_gemm_mfma(const unsigned short* __restrict__ A, int lda, int Kreal, int Kpad,
                 const unsigned short* __restrict__ Bhi,
                 const unsigned short* __restrict__ Blo, int ldb,
                 const float* __restrict__ bias,
                 const float* __restrict__ a_scale, const float* __restrict__ a_shift,
                 unsigned short* __restrict__ C, int ldc, int M, int Nc, int relu) {
    __shared__ unsigned short As[GBM][GBK];   // 16 KB
    __shared__ unsigned short Bh[GBN][GBK];   // 8 KB
    __shared__ unsigned short Bl[GBN][GBK];   // 8 KB

    int tid = threadIdx.x;
    int wave = tid >> 6, lane = tid & 63;
    int quad = lane >> 4, l16 = lane & 15;
    int row0 = blockIdx.y * GBM;
    int col0 = blockIdx.x * GBN;
    int has_aff = (a_scale != nullptr);

    float4v acc[2][4];
    #pragma unroll
    for (int i = 0; i < 2; ++i)
        #pragma unroll
        for (int j = 0; j < 4; ++j) acc[i][j] = (float4v){0.f, 0.f, 0.f, 0.f};

    for (int k0 = 0; k0 < Kpad; k0 += GBK) {
        // ---- stage A: 128 rows x 16 chunks(4 bf16, 8B) ----
        #pragma unroll
        for (int i = 0; i < 8; ++i) {
            int cidx = tid + i * 256;            // 0..2047
            int r = cidx >> 4;
            int kc = (cidx & 15) << 2;           // 0..60
            int gr = row0 + r; if (gr >= M) gr = M - 1;
            int gk = k0 + kc;
            ushort4 v = make_ushort4(0, 0, 0, 0);
            if (gk < Kreal) {
                v = *(const ushort4*)(A + (size_t)gr * lda + gk);
                if (has_aff) {
                    float fx = u2f(v.x) * a_scale[gk + 0] + a_shift[gk + 0];
                    float fy = u2f(v.y) * a_scale[gk + 1] + a_shift[gk + 1];
                    float fz = u2f(v.z) * a_scale[gk + 2] + a_shift[gk + 2];
                    float fw = u2f(v.w) * a_scale[gk + 3] + a_shift[gk + 3];
                    v = make_ushort4(f2bu(fx), f2bu(fy), f2bu(fz), f2bu(fw));
                }
            }
            *(ushort4*)(&As[r][kc]) = v;
        }
        // ---- stage B hi/lo: 64 rows x 8 chunks(8 bf16, 16B), no guards (padded) ----
        #pragma unroll
        for (int i = 0; i < 2; ++i) {
            int cidx = tid + i * 256;            // 0..511
            int n = cidx >> 3;
            int kc = (cidx & 7) << 3;            // 0..56
            size_t goff = (size_t)(col0 + n) * ldb + k0 + kc;
            *(uint4*)(&Bh[n][kc]) = *(const uint4*)(Bhi + goff);
            *(uint4*)(&Bl[n][kc]) = *(const uint4*)(Blo + goff);
        }
        __syncthreads();

        int mbase = wave * 32;
        #pragma unroll
        for (int ks = 0; ks < GBK; ks += 32) {
            short8 a0 = *(const short8*)(&As[mbase + l16][ks + quad * 8]);
            short8 a1 = *(const short8*)(&As[mbase + 16 + l16][ks + quad * 8]);
            #pragma unroll
            for (int nt = 0; nt < 4; ++nt) {
                short8 bh = *(const short8*)(&Bh[nt * 16 + l16][ks + quad * 8]);
                short8 bl = *(const short8*)(&Bl[nt * 16 + l16][ks + quad * 8]);
                acc[0][nt] = __builtin_amdgcn_mfma_f32_16x16x32_bf16(a0, bh, acc[0][nt], 0, 0, 0);
                acc[0][nt] = __builtin_amdgcn_mfma_f32_16x16x32_bf16(a0, bl, acc[0][nt], 0, 0, 0);
                acc[1][nt] = __builtin_amdgcn_mfma_f32_16x16x32_bf16(a1, bh, acc[1][nt], 0, 0, 0);
                acc[1][nt] = __builtin_amdgcn_mfma_f32_16x16x32_bf16(a1, bl, acc[1][nt], 0, 0, 0);
            }
        }
        __syncthreads();
    }

    // epilogue: C/D layout col=lane&15, row=quad*4+reg (m89-verified)
    #pragma unroll
    for (int mt = 0; mt < 2; ++mt) {
        int rbase = row0 + wave * 32 + mt * 16 + quad * 4;
        #pragma unroll
        for (int nt = 0; nt < 4; ++nt) {
            int c = col0 + nt * 16 + l16;
            if (c >= Nc) continue;
            float bs = bias[c];
            #pragma unroll
            for (int i = 0; i < 4; ++i) {
                int r = rbase + i;
                if (r >= M) continue;
                float v = acc[mt][nt][i] + bs;
                if (relu) v = fmaxf(v, 0.f);
                C[(size_t)r * ldc + c] = f2bu(v);
            }
        }
    }
}

// ---------------- logits GEMM (fp32 vector): C = scale * A @ B^T ----------------
#define BM 64
#define BN 64
#define BKK 20

__global__ void k_gemm_nt(const float* __restrict__ A, const float* __restrict__ B,
                          float* __restrict__ C, int M, int Nc, int K, float scale) {
    __shared__ float As[BKK][BM];
    __shared__ float Bs[BKK][BN];
    int tid = threadIdx.x;
    int tx = tid & 15, ty = tid >> 4;
    int row0 = blockIdx.y * BM;
    int col0 = blockIdx.x * BN;
    float acc[4][4] = {};
    for (int k0 = 0; k0 < K; k0 += BKK) {
        for (int t = tid; t < BM * BKK; t += 256) {
            int r = t / BKK, kk = t % BKK;
            int gr = row0 + r, gk = k0 + kk;
            As[kk][r] = (gr < M && gk < K) ? A[(size_t)gr * K + gk] : 0.f;
        }
        for (int t = tid; t < BN * BKK; t += 256) {
            int c = t / BKK, kk = t % BKK;
            int gc = col0 + c, gk = k0 + kk;
            Bs[kk][c] = (gc < Nc && gk < K) ? B[(size_t)gc * K + gk] : 0.f;
        }
        __syncthreads();
        #pragma unroll
        for (int kk = 0; kk < BKK; ++kk) {
            float4 a4 = reinterpret_cast<const float4*>(&As[kk][0])[ty];
            float4 b4 = reinterpret_cast<const float4*>(&Bs[kk][0])[tx];
            float a[4] = {a4.x, a4.y, a4.z, a4.w};
            float b[4] = {b4.x, b4.y, b4.z, b4.w};
            #pragma unroll
            for (int i = 0; i < 4; ++i)
                #pragma unroll
                for (int j = 0; j < 4; ++j)
                    acc[i][j] += a[i] * b[j];
        }
        __syncthreads();
    }
    #pragma unroll
    for (int i = 0; i < 4; ++i) {
        int gr = row0 + ty * 4 + i;
        if (gr >= M) continue;
        #pragma unroll
        for (int j = 0; j < 4; ++j) {
            int gc = col0 + tx * 4 + j;
            if (gc >= Nc) continue;
            C[(size_t)gr * Nc + gc] = acc[i][j] * scale;
        }
    }
}

// ---------------- batch norm stats (on pre-BN h) ----------------

__global__ void k_colstats(const bf16* __restrict__ h, float* __restrict__ stats,
                           int N, int chunk) {
    int c = threadIdx.x;
    if (c >= EMB) return;
    int r0 = blockIdx.x * chunk;
    int r1 = min(N, r0 + chunk);
    float s = 0.f, q = 0.f;
    for (int r = r0; r < r1; ++r) {
        float v = b2f(h[(size_t)r * EMB + c]);
        s += v; q += v * v;
    }
    atomicAdd(&stats[c], s);
    atomicAdd(&stats[EMB + c], q);
}

__global__ void k_bn_prep(float* __restrict__ stats, const float* __restrict__ gamma,
                          const float* __restrict__ beta, float invN) {
    int c = threadIdx.x;
    if (c >= EMB) return;
    float mean = stats[c] * invN;
    float var = stats[EMB + c] * invN - mean * mean;
    float scale = gamma[c] * rsqrtf(var + BN_EPS);
    stats[c] = scale;
    stats[EMB + c] = beta[c] - mean * scale;
}

// ---------------- fused pool + mean + L2 normalize (proj pitch 320) ----------------

__global__ void k_poolnorm(const bf16* __restrict__ proj, const int* __restrict__ gstart,
                           float* __restrict__ f) {
    int g = blockIdx.x, t = threadIdx.x;
    int s = gstart[g], e = gstart[g + 1];
    float sum = 0.f;
    if (t < EMB)
        for (int r = s; r < e; ++r) sum += b2f(proj[(size_t)r * AGGP + t]);
    float cnt = fmaxf((float)(e - s), 1.f);
    float m = sum / cnt;
    float q = (t < EMB) ? m * m : 0.f;
    for (int off = 32; off > 0; off >>= 1) q += __shfl_down(q, off, 64);
    __shared__ float red[5];
    int lane = t & 63, wid = t >> 6;
    if (lane == 0) red[wid] = q;
    __syncthreads();
    float tot = red[0] + red[1] + red[2] + red[3] + red[4];
    float invn = 1.f / fmaxf(sqrtf(tot), 1e-12f);
    if (t < EMB) f[(size_t)g * EMB + t] = m * invn;
}

// ---------------- host ----------------

static inline int ceil_div(int a, int b) { return (a + b - 1) / b; }

extern "C" void kernel_launch(void* const* d_in, const int* in_sizes, int n_in,
                              void* d_out, int out_size, void* d_ws, size_t ws_size,
                              hipStream_t stream) {
    const int N = in_sizes[0] / 2;    // 100000
    const int E = in_sizes[1] / 2;    // 400000

    const int* x[2]  = { (const int*)d_in[0], (const int*)d_in[4] };
    const int* ei[2] = { (const int*)d_in[1], (const int*)d_in[5] };
    const int* ea[2] = { (const int*)d_in[2], (const int*)d_in[6] };
    const int* bt[2] = { (const int*)d_in[3], (const int*)d_in[7] };
    const float* atom1 = (const float*)d_in[8];
    const float* atom2 = (const float*)d_in[9];
    const float* ee1 = (const float*)d_in[10];   // [5,6,300]
    const float* ee2 = (const float*)d_in[11];   // [5,3,300]
    const float* w1  = (const float*)d_in[12];   // [5,300,600]
    const float* b1  = (const float*)d_in[13];   // [5,600]
    const float* w2  = (const float*)d_in[14];   // [5,600,300]
    const float* b2  = (const float*)d_in[15];   // [5,300]
    const float* gam = (const float*)d_in[16];
    const float* bet = (const float*)d_in[17];
    const float* pw  = (const float*)d_in[18];   // [300,300]
    const float* pb  = (const float*)d_in[19];
    float* out = (float*)d_out;

    // ---- workspace ----
    char* wsb = (char*)d_ws;
    bf16* h    = (bf16*)(wsb);
    bf16* agg  = (bf16*)(wsb + 60000000);
    bf16* hid  = (bf16*)(wsb + 124000000);
    float* f0  = (float*)(wsb + 244000000);
    float* f1  = (float*)(wsb + 248915200);

    // ---- d_out scratch (consumed before logits GEMM) ----
    int* deg      = (int*)d_out;              // N+1
    int* rowstart = deg + (N + 1);            // N+1
    int* cursor   = rowstart + (N + 1);       // N
    int* esorted  = cursor + N;               // E
    int* csum     = esorted + E;              // 512
    int* coff     = csum + 512;               // 512
    int* gstart   = coff + 512;               // 4097
    float* stats  = (float*)(gstart + 4097);  // 600
    char* splits  = (char*)d_out + 2824192;   // 256B-aligned
    unsigned short* w1hi = (unsigned short*)(splits);               // 5*640*320
    unsigned short* w1lo = (unsigned short*)(splits + 2048000);
    unsigned short* w2hi = (unsigned short*)(splits + 4096000);     // 5*320*640
    unsigned short* w2lo = (unsigned short*)(splits + 6144000);
    unsigned short* pjhi = (unsigned short*)(splits + 8192000);     // 320*320
    unsigned short* pjlo = (unsigned short*)(splits + 8396800);

    const int TB = 256;
    const int nh_blocks = ceil_div(N * EMBC, TB);
    const int na_blocks = ceil_div(N * AGGC, TB);
    const int nchunks = ceil_div(N + 1, 256);
    const int chunk = ceil_div(N, 256);
    const float invN = 1.f / (float)N;

    // ---- split all weights (once; shared by both branches) ----
    for (int l = 0; l < 5; ++l) {
        k_split<<<ceil_div(640 * 320, TB), TB, 0, stream>>>(
            w1 + (size_t)l * EMB * HID, EMB, HID, 320, 640,
            w1hi + (size_t)l * 640 * 320, w1lo + (size_t)l * 640 * 320);
        k_split<<<ceil_div(320 * 640, TB), TB, 0, stream>>>(
            w2 + (size_t)l * HID * EMB, HID, EMB, 640, 320,
            w2hi + (size_t)l * 320 * 640, w2lo + (size_t)l * 320 * 640);
    }
    k_split<<<ceil_div(320 * 320, TB), TB, 0, stream>>>(pw, EMB, EMB, 320, 320, pjhi, pjlo);

    dim3 g1(10, ceil_div(N, GBM));   // Npad=640
    dim3 g2(5, ceil_div(N, GBM));    // Npad=320
    dim3 gl(ceil_div(NGRAPH, BN), ceil_div(NGRAPH, BM));

    for (int br = 0; br < 2; ++br) {
        float* fout = br == 0 ? f0 : f1;
        // ---- CSR build ----
        k_zero_i<<<ceil_div(N + 1, TB), TB, 0, stream>>>(deg, N + 1);
        k_hist<<<ceil_div(E, TB), TB, 0, stream>>>(ei[br], deg, E);
        k_chunksum<<<nchunks, 256, 0, stream>>>(deg, csum, N + 1);
        k_scanchunks<<<1, 64, 0, stream>>>(csum, coff, nchunks);
        k_scan2<<<nchunks, 256, 0, stream>>>(deg, coff, rowstart, N + 1);
        k_initcursor<<<ceil_div(N, TB), TB, 0, stream>>>(rowstart, cursor, N);
        k_fill<<<ceil_div(E, TB), TB, 0, stream>>>(ei[br], cursor, esorted, E);
        k_gstart<<<ceil_div(NGRAPH + 1, TB), TB, 0, stream>>>(bt[br], gstart, N);
        // ---- encoder ----
        k_init_h<<<nh_blocks, TB, 0, stream>>>(x[br], (const float4*)atom1,
                                               (const float4*)atom2, (bf4*)h, N);
        for (int l = 0; l < 5; ++l) {
            const float* e1 = ee1 + (size_t)l * 6 * EMB;
            const float* e2 = ee2 + (size_t)l * 3 * EMB;
            // aggregate applies BN(l-1) affine + relu on the fly (l>0)
            k_aggregate<<<na_blocks, TB, 0, stream>>>((const bf4*)h, ei[br], ea[br],
                                                      (const float4*)e1, (const float4*)e2,
                                                      rowstart, esorted, stats, l > 0,
                                                      (bf4*)agg, N, E);
            k_gemm_mfma<<<g1, 256, 0, stream>>>(
                (const unsigned short*)agg, AGGP, AGGP, AGGP,
                w1hi + (size_t)l * 640 * 320, w1lo + (size_t)l * 640 * 320, 320,
                b1 + (size_t)l * HID, nullptr, nullptr,
                (unsigned short*)hid, HID, N, HID, 1);
            k_gemm_mfma<<<g2, 256, 0, stream>>>(
                (const unsigned short*)hid, HID, HID, 640,
                w2hi + (size_t)l * 320 * 640, w2lo + (size_t)l * 320 * 640, 640,
                b2 + (size_t)l * EMB, nullptr, nullptr,
                (unsigned short*)h, EMB, N, EMB, 0);
            k_zero_f<<<ceil_div(2 * EMB, TB), TB, 0, stream>>>(stats, 2 * EMB);
            k_colstats<<<256, 320, 0, stream>>>(h, stats, N, chunk);
            k_bn_prep<<<1, 320, 0, stream>>>(stats, gam + (size_t)l * EMB,
                                             bet + (size_t)l * EMB, invN);
        }
        // projector: A-staging applies BN(4) affine (no relu); output -> agg (pitch 320)
        k_gemm_mfma<<<g2, 256, 0, stream>>>(
            (const unsigned short*)h, EMB, EMB, 320,
            pjhi, pjlo, 320, pb, stats, stats + EMB,
            (unsigned short*)agg, AGGP, N, EMB, 0);
        // fused pool + mean + L2 norm
        k_poolnorm<<<NGRAPH, 320, 0, stream>>>(agg, gstart, fout);
    }
    // logits = f0 @ f1^T / TEMP (overwrites d_out scratch)
    k_gemm_nt<<<gl, 256, 0, stream>>>(f0, f1, out, NGRAPH, NGRAPH, EMB, INV_TEMP);
}

// Round 4
// 5894.167 us; speedup vs baseline: 3.0487x; 1.5244x over previous
//
#include <hip/hip_runtime.h>
#include <hip/hip_bf16.h>

// 5-layer GNN encoder x2 branches + projector + mean-pool + L2norm + logits.
// Round 4: MFMA GEMM rebuilt m97-style: global_load_lds(16B) staging,
// 128x128x64 tile, XOR source-swizzle (bank-conflict-free ds_read_b128 with
// an LDS layout that stays global_load_lds-compatible). Split-weight hi/lo
// numerics unchanged. BN affine for projector via k_bncopy pre-pass.
//
// d_ws layout (bytes), total 253,830,400:
//   h    bf16 [N,300]  @ 0            pre-BN layer output
//   agg  bf16 [N,320]  @ 60,000,000   K-padded zeros in 300..319
//   hid  bf16 [N,600]  @ 124,000,000  (also reused as BN(h) copy [N,320] for projector)
//   f0   f32  [4096,300] @ 244,000,000
//   f1   f32  [4096,300] @ 248,915,200
// d_out doubles as scratch (CSR + stats + split weights ~12.3MB), consumed
// before the final logits GEMM overwrites it.

#define EMB 300
#define EMBC 75       // 300/4 chunks (h pitch 300)
#define AGGP 320      // agg row pitch (elems)
#define AGGC 80
#define HID 600
#define NGRAPH 4096
#define BN_EPS 1e-5f
#define INV_TEMP 25.0f

typedef __hip_bfloat16 bf16;
struct __align__(8) bf4 { bf16 x, y, z, w; };
typedef __attribute__((ext_vector_type(8))) short short8;
typedef __attribute__((ext_vector_type(4))) float float4v;

__device__ inline float b2f(bf16 v) { return __bfloat162float(v); }
__device__ inline bf16 f2b(float v) { return __float2bfloat16(v); }
__device__ inline unsigned short f2bu(float f) {
    bf16 b = __float2bfloat16(f); unsigned short u; __builtin_memcpy(&u, &b, 2); return u;
}

// async global->LDS, 16 bytes per lane; LDS dest = uniform base + lane*16
typedef const unsigned int __attribute__((address_space(1)))* gas_t;
typedef unsigned int __attribute__((address_space(3)))* las_t;
__device__ __forceinline__ void gl_lds16(const unsigned short* g, unsigned short* l) {
    __builtin_amdgcn_global_load_lds((gas_t)g, (las_t)l, 16, 0, 0);
}

// ---------------- small utility ----------------

__global__ void k_zero_f(float* __restrict__ p, int n) {
    int i = blockIdx.x * blockDim.x + threadIdx.x;
    if (i < n) p[i] = 0.f;
}
__global__ void k_zero_i(int* __restrict__ p, int n) {
    int i = blockIdx.x * blockDim.x + threadIdx.x;
    if (i < n) p[i] = 0;
}

// ---------------- weight split: W[K][N] f32 -> Wt_hi/lo[Npad][Kpad] bf16 ----------------

__global__ void k_split(const float* __restrict__ W, int K, int N, int Kpad, int Npad,
                        unsigned short* __restrict__ hi, unsigned short* __restrict__ lo) {
    int idx = blockIdx.x * blockDim.x + threadIdx.x;
    if (idx >= Npad * Kpad) return;
    int n = idx / Kpad, k = idx % Kpad;
    float v = (n < N && k < K) ? W[(size_t)k * N + n] : 0.f;
    bf16 h = __float2bfloat16(v);
    float rem = v - __bfloat162float(h);
    bf16 l = __float2bfloat16(rem);
    unsigned short hu, lu;
    __builtin_memcpy(&hu, &h, 2); __builtin_memcpy(&lu, &l, 2);
    hi[idx] = hu; lo[idx] = lu;
}

// ---------------- CSR build (dst-sorted edge ids) ----------------

__global__ void k_hist(const int* __restrict__ ei, int* __restrict__ deg, int E) {
    int e = blockIdx.x * blockDim.x + threadIdx.x;
    if (e < E) atomicAdd(&deg[ei[E + e]], 1);
}

__global__ void k_chunksum(const int* __restrict__ deg, int* __restrict__ csum, int total) {
    __shared__ int s[256];
    int t = threadIdx.x, i = blockIdx.x * 256 + t;
    s[t] = (i < total) ? deg[i] : 0;
    __syncthreads();
    for (int off = 128; off > 0; off >>= 1) {
        if (t < off) s[t] += s[t + off];
        __syncthreads();
    }
    if (t == 0) csum[blockIdx.x] = s[0];
}

__global__ void k_scanchunks(const int* __restrict__ csum, int* __restrict__ coff, int n) {
    if (threadIdx.x == 0) {
        int acc = 0;
        for (int b = 0; b < n; ++b) { coff[b] = acc; acc += csum[b]; }
    }
}

__global__ void k_scan2(const int* __restrict__ deg, const int* __restrict__ coff,
                        int* __restrict__ rowstart, int total) {
    __shared__ int s[256];
    int t = threadIdx.x, b = blockIdx.x, i = b * 256 + t;
    int v = (i < total) ? deg[i] : 0;
    s[t] = v;
    __syncthreads();
    for (int off = 1; off < 256; off <<= 1) {
        int u = (t >= off) ? s[t - off] : 0;
        __syncthreads();
        s[t] += u;
        __syncthreads();
    }
    if (i < total) rowstart[i] = coff[b] + s[t] - v;
}

__global__ void k_initcursor(const int* __restrict__ rowstart, int* __restrict__ cur, int N) {
    int i = blockIdx.x * blockDim.x + threadIdx.x;
    if (i < N) cur[i] = rowstart[i];
}

__global__ void k_fill(const int* __restrict__ ei, int* __restrict__ cur,
                       int* __restrict__ esorted, int E) {
    int e = blockIdx.x * blockDim.x + threadIdx.x;
    if (e < E) {
        int p = atomicAdd(&cur[ei[E + e]], 1);
        esorted[p] = e;
    }
}

__global__ void k_gstart(const int* __restrict__ batch, int* __restrict__ gstart, int N) {
    int g = blockIdx.x * blockDim.x + threadIdx.x;
    if (g > NGRAPH) return;
    int lo = 0, hi = N;
    while (lo < hi) { int mid = (lo + hi) >> 1; if (batch[mid] < g) lo = mid + 1; else hi = mid; }
    gstart[g] = lo;
}

// ---------------- node init & aggregation (with fused BN affine) ----------------

__global__ void k_init_h(const int* __restrict__ x,
                         const float4* __restrict__ ae1,
                         const float4* __restrict__ ae2,
                         bf4* __restrict__ h4, int N) {
    int idx = blockIdx.x * blockDim.x + threadIdx.x;
    if (idx >= N * EMBC) return;
    int i = idx / EMBC, j = idx % EMBC;
    int a0 = x[2 * i], a1 = x[2 * i + 1];
    float4 u = ae1[a0 * EMBC + j];
    float4 v = ae2[a1 * EMBC + j];
    bf4 r = { f2b(u.x + v.x), f2b(u.y + v.y), f2b(u.z + v.z), f2b(u.w + v.w) };
    h4[idx] = r;
}

__global__ void k_aggregate(const bf4* __restrict__ h4,
                            const int* __restrict__ ei,
                            const int* __restrict__ ea,
                            const float4* __restrict__ e1,  // [6,75] f4
                            const float4* __restrict__ e2,  // [3,75] f4
                            const int* __restrict__ rowstart,
                            const int* __restrict__ esorted,
                            const float* __restrict__ stats, int use_aff,
                            bf4* __restrict__ agg4, int N, int E) {
    int idx = blockIdx.x * blockDim.x + threadIdx.x;
    if (idx >= N * AGGC) return;
    int n = idx / AGGC, j = idx % AGGC;
    if (j >= EMBC) {
        bf4 z = { f2b(0.f), f2b(0.f), f2b(0.f), f2b(0.f) };
        agg4[idx] = z;
        return;
    }
    float4 sc = make_float4(1.f, 1.f, 1.f, 1.f);
    float4 sh = make_float4(0.f, 0.f, 0.f, 0.f);
    if (use_aff) {
        sc = ((const float4*)stats)[j];
        sh = ((const float4*)(stats + EMB))[j];
    }
    bf4 hv = h4[(size_t)n * EMBC + j];
    float hx = b2f(hv.x), hy = b2f(hv.y), hz = b2f(hv.z), hw = b2f(hv.w);
    if (use_aff) {
        hx = fmaxf(hx * sc.x + sh.x, 0.f); hy = fmaxf(hy * sc.y + sh.y, 0.f);
        hz = fmaxf(hz * sc.z + sh.z, 0.f); hw = fmaxf(hw * sc.w + sh.w, 0.f);
    }
    float4 s1 = e1[4 * EMBC + j];
    float4 s2 = e2[j];
    float ax = hx + s1.x + s2.x, ay = hy + s1.y + s2.y;
    float az = hz + s1.z + s2.z, aw = hw + s1.w + s2.w;
    int p0 = rowstart[n], p1 = rowstart[n + 1];
    for (int p = p0; p < p1; ++p) {
        int e = esorted[p];
        int s = ei[e];
        int a0 = ea[2 * e], a1 = ea[2 * e + 1];
        bf4 hs = h4[(size_t)s * EMBC + j];
        float gx = b2f(hs.x), gy = b2f(hs.y), gz = b2f(hs.z), gw = b2f(hs.w);
        if (use_aff) {
            gx = fmaxf(gx * sc.x + sh.x, 0.f); gy = fmaxf(gy * sc.y + sh.y, 0.f);
            gz = fmaxf(gz * sc.z + sh.z, 0.f); gw = fmaxf(gw * sc.w + sh.w, 0.f);
        }
        float4 v1 = e1[a0 * EMBC + j];
        float4 v2 = e2[a1 * EMBC + j];
        ax += gx + v1.x + v2.x; ay += gy + v1.y + v2.y;
        az += gz + v1.z + v2.z; aw += gw + v1.w + v2.w;
    }
    bf4 r = { f2b(ax), f2b(ay), f2b(az), f2b(aw) };
    agg4[idx] = r;
}

// BN(h) copy for projector: dst[N,320] = scale*h + shift (no relu), pad zeroed
__global__ void k_bncopy(const bf4* __restrict__ h4, const float* __restrict__ stats,
                         bf4* __restrict__ dst, int N) {
    int idx = blockIdx.x * blockDim.x + threadIdx.x;
    if (idx >= N * AGGC) return;
    int n = idx / AGGC, j = idx % AGGC;
    if (j >= EMBC) {
        bf4 z = { f2b(0.f), f2b(0.f), f2b(0.f), f2b(0.f) };
        dst[idx] = z;
        return;
    }
    float4 sc = ((const float4*)stats)[j];
    float4 sh = ((const float4*)(stats + EMB))[j];
    bf4 v = h4[(size_t)n * EMBC + j];
    bf4 r = { f2b(b2f(v.x) * sc.x + sh.x), f2b(b2f(v.y) * sc.y + sh.y),
              f2b(b2f(v.z) * sc.z + sh.z), f2b(b2f(v.w) * sc.w + sh.w) };
    dst[idx] = r;
}

// ---------------- MFMA GEMM: C_bf16[M,Nc] = A_bf16[M,K] @ (Bhi+Blo)^T + bias --------
// B transposed+padded [Npad][Kpad], Npad multiple of 128, K zero-padded.
// Tile 128x128x64, 4 waves, each 32 rows x 128 cols. global_load_lds staging.
// LDS[r][slot] holds global K-chunk (slot ^ (r&7)): bank-conflict-free
// ds_read_b128 while staying contiguous-in-lane-order for global_load_lds.
// Async path needs rows readable over [k0, k0+64); tail (Kasync..Kpad) staged
// manually with per-element guards (A only; B always padded).

#define GBM 128
#define GBN 128
#define GBK 64

__global__ __launch_bounds__(256)
void k_gemm_mfma(const unsigned short* __restrict__ A, int lda, int Kreal,
                 int Kpad, int Kasync,
                 const unsigned short* __restrict__ Bhi,
                 const unsigned short* __restrict__ Blo, int ldb,
                 const float* __restrict__ bias,
                 unsigned short* __restrict__ C, int ldc, int M, int Nc, int relu) {
    __shared__ unsigned short As[GBM][GBK];   // 16 KB
    __shared__ unsigned short Bh[GBN][GBK];   // 16 KB
    __shared__ unsigned short Bl[GBN][GBK];   // 16 KB

    int tid = threadIdx.x;
    int wv = tid >> 6, lane = tid & 63;
    int quad = lane >> 4, l16 = lane & 15;
    int lrow = lane >> 3;          // 0..7 within an 8-row staging group
    int gchunk = (lane & 7) ^ lrow; // swizzled source chunk for this lane's slot
    int sw = lane & 7;             // == l16 & 7, compute-side swizzle key
    int row0 = blockIdx.y * GBM;
    int col0 = blockIdx.x * GBN;

    float4v acc[2][8];
    #pragma unroll
    for (int i = 0; i < 2; ++i)
        #pragma unroll
        for (int j = 0; j < 8; ++j) acc[i][j] = (float4v){0.f, 0.f, 0.f, 0.f};

    for (int k0 = 0; k0 < Kpad; k0 += GBK) {
        if (k0 < Kasync) {
            // ---- async staging: A 4 insts/wave, Bhi 4, Blo 4 ----
            #pragma unroll
            for (int j = 0; j < 4; ++j) {
                int r = 32 * wv + 8 * j + lrow;
                int gr = min(row0 + r, M - 1);
                gl_lds16(A + (size_t)gr * lda + k0 + gchunk * 8, &As[32 * wv + 8 * j][0]);
            }
            #pragma unroll
            for (int j = 0; j < 4; ++j) {
                int r = 32 * wv + 8 * j + lrow;
                size_t go = (size_t)(col0 + r) * ldb + k0 + gchunk * 8;
                gl_lds16(Bhi + go, &Bh[32 * wv + 8 * j][0]);
                gl_lds16(Blo + go, &Bl[32 * wv + 8 * j][0]);
            }
        } else {
            // ---- manual A tail with per-element K guard; B still async ----
            #pragma unroll
            for (int i = 0; i < 4; ++i) {
                int cidx = tid + i * 256;        // 0..1023 = 128 rows x 8 slots
                int r = cidx >> 3, s = cidx & 7;
                int g = s ^ (r & 7);
                int gr = min(row0 + r, M - 1);
                unsigned short tmp[8];
                #pragma unroll
                for (int t = 0; t < 8; ++t) {
                    int gk = k0 + g * 8 + t;
                    tmp[t] = (gk < Kreal) ? A[(size_t)gr * lda + gk] : (unsigned short)0;
                }
                uint4 w; __builtin_memcpy(&w, tmp, 16);
                *(uint4*)(&As[r][s * 8]) = w;
            }
            #pragma unroll
            for (int j = 0; j < 4; ++j) {
                int r = 32 * wv + 8 * j + lrow;
                size_t go = (size_t)(col0 + r) * ldb + k0 + gchunk * 8;
                gl_lds16(Bhi + go, &Bh[32 * wv + 8 * j][0]);
                gl_lds16(Blo + go, &Bl[32 * wv + 8 * j][0]);
            }
        }
        __syncthreads();

        int mbase = wv * 32;
        #pragma unroll
        for (int ks = 0; ks < GBK; ks += 32) {
            int lc = (ks >> 3) + quad;           // logical chunk
            int pc = lc ^ sw;                    // physical (swizzled) slot
            short8 a0 = *(const short8*)(&As[mbase + l16][pc * 8]);
            short8 a1 = *(const short8*)(&As[mbase + 16 + l16][pc * 8]);
            #pragma unroll
            for (int nt = 0; nt < 8; ++nt) {
                short8 bh = *(const short8*)(&Bh[nt * 16 + l16][pc * 8]);
                short8 bl = *(const short8*)(&Bl[nt * 16 + l16][pc * 8]);
                acc[0][nt] = __builtin_amdgcn_mfma_f32_16x16x32_bf16(a0, bh, acc[0][nt], 0, 0, 0);
                acc[0][nt] = __builtin_amdgcn_mfma_f32_16x16x32_bf16(a0, bl, acc[0][nt], 0, 0, 0);
                acc[1][nt] = __builtin_amdgcn_mfma_f32_16x16x32_bf16(a1, bh, acc[1][nt], 0, 0, 0);
                acc[1][nt] = __builtin_amdgcn_mfma_f32_16x16x32_bf16(a1, bl, acc[1][nt], 0, 0, 0);
            }
        }
        __syncthreads();
    }

    // epilogue: C/D layout col=lane&15, row=quad*4+reg (m89-verified)
    #pragma unroll
    for (int mt = 0; mt < 2; ++mt) {
        int rbase = row0 + wv * 32 + mt * 16 + quad * 4;
        #pragma unroll
        for (int nt = 0; nt < 8; ++nt) {
            int c = col0 + nt * 16 + l16;
            if (c >= Nc) continue;
            float bs = bias[c];
            #pragma unroll
            for (int i = 0; i < 4; ++i) {
                int r = rbase + i;
                if (r >= M) continue;
                float v = acc[mt][nt][i] + bs;
                if (relu) v = fmaxf(v, 0.f);
                C[(size_t)r * ldc + c] = f2bu(v);
            }
        }
    }
}

// ---------------- logits GEMM (fp32 vector): C = scale * A @ B^T ----------------
#define BM 64
#define BN 64
#define BKK 20

__global__ void k_gemm_nt(const float* __restrict__ A, const float* __restrict__ B,
                          float* __restrict__ C, int M, int Nc, int K, float scale) {
    __shared__ float As[BKK][BM];
    __shared__ float Bs[BKK][BN];
    int tid = threadIdx.x;
    int tx = tid & 15, ty = tid >> 4;
    int row0 = blockIdx.y * BM;
    int col0 = blockIdx.x * BN;
    float acc[4][4] = {};
    for (int k0 = 0; k0 < K; k0 += BKK) {
        for (int t = tid; t < BM * BKK; t += 256) {
            int r = t / BKK, kk = t % BKK;
            int gr = row0 + r, gk = k0 + kk;
            As[kk][r] = (gr < M && gk < K) ? A[(size_t)gr * K + gk] : 0.f;
        }
        for (int t = tid; t < BN * BKK; t += 256) {
            int c = t / BKK, kk = t % BKK;
            int gc = col0 + c, gk = k0 + kk;
            Bs[kk][c] = (gc < Nc && gk < K) ? B[(size_t)gc * K + gk] : 0.f;
        }
        __syncthreads();
        #pragma unroll
        for (int kk = 0; kk < BKK; ++kk) {
            float4 a4 = reinterpret_cast<const float4*>(&As[kk][0])[ty];
            float4 b4 = reinterpret_cast<const float4*>(&Bs[kk][0])[tx];
            float a[4] = {a4.x, a4.y, a4.z, a4.w};
            float b[4] = {b4.x, b4.y, b4.z, b4.w};
            #pragma unroll
            for (int i = 0; i < 4; ++i)
                #pragma unroll
                for (int j = 0; j < 4; ++j)
                    acc[i][j] += a[i] * b[j];
        }
        __syncthreads();
    }
    #pragma unroll
    for (int i = 0; i < 4; ++i) {
        int gr = row0 + ty * 4 + i;
        if (gr >= M) continue;
        #pragma unroll
        for (int j = 0; j < 4; ++j) {
            int gc = col0 + tx * 4 + j;
            if (gc >= Nc) continue;
            C[(size_t)gr * Nc + gc] = acc[i][j] * scale;
        }
    }
}

// ---------------- batch norm stats ----------------

__global__ void k_colstats(const bf16* __restrict__ h, float* __restrict__ stats,
                           int N, int chunk) {
    int c = threadIdx.x;
    if (c >= EMB) return;
    int r0 = blockIdx.x * chunk;
    int r1 = min(N, r0 + chunk);
    float s = 0.f, q = 0.f;
    for (int r = r0; r < r1; ++r) {
        float v = b2f(h[(size_t)r * EMB + c]);
        s += v; q += v * v;
    }
    atomicAdd(&stats[c], s);
    atomicAdd(&stats[EMB + c], q);
}

__global__ void k_bn_prep(float* __restrict__ stats, const float* __restrict__ gamma,
                          const float* __restrict__ beta, float invN) {
    int c = threadIdx.x;
    if (c >= EMB) return;
    float mean = stats[c] * invN;
    float var = stats[EMB + c] * invN - mean * mean;
    float scale = gamma[c] * rsqrtf(var + BN_EPS);
    stats[c] = scale;
    stats[EMB + c] = beta[c] - mean * scale;
}

// ---------------- fused pool + mean + L2 normalize (proj pitch 320) ----------------

__global__ void k_poolnorm(const bf16* __restrict__ proj, const int* __restrict__ gstart,
                           float* __restrict__ f) {
    int g = blockIdx.x, t = threadIdx.x;
    int s = gstart[g], e = gstart[g + 1];
    float sum = 0.f;
    if (t < EMB)
        for (int r = s; r < e; ++r) sum += b2f(proj[(size_t)r * AGGP + t]);
    float cnt = fmaxf((float)(e - s), 1.f);
    float m = sum / cnt;
    float q = (t < EMB) ? m * m : 0.f;
    for (int off = 32; off > 0; off >>= 1) q += __shfl_down(q, off, 64);
    __shared__ float red[5];
    int lane = t & 63, wid = t >> 6;
    if (lane == 0) red[wid] = q;
    __syncthreads();
    float tot = red[0] + red[1] + red[2] + red[3] + red[4];
    float invn = 1.f / fmaxf(sqrtf(tot), 1e-12f);
    if (t < EMB) f[(size_t)g * EMB + t] = m * invn;
}

// ---------------- host ----------------

static inline int ceil_div(int a, int b) { return (a + b - 1) / b; }

extern "C" void kernel_launch(void* const* d_in, const int* in_sizes, int n_in,
                              void* d_out, int out_size, void* d_ws, size_t ws_size,
                              hipStream_t stream) {
    const int N = in_sizes[0] / 2;    // 100000
    const int E = in_sizes[1] / 2;    // 400000

    const int* x[2]  = { (const int*)d_in[0], (const int*)d_in[4] };
    const int* ei[2] = { (const int*)d_in[1], (const int*)d_in[5] };
    const int* ea[2] = { (const int*)d_in[2], (const int*)d_in[6] };
    const int* bt[2] = { (const int*)d_in[3], (const int*)d_in[7] };
    const float* atom1 = (const float*)d_in[8];
    const float* atom2 = (const float*)d_in[9];
    const float* ee1 = (const float*)d_in[10];   // [5,6,300]
    const float* ee2 = (const float*)d_in[11];   // [5,3,300]
    const float* w1  = (const float*)d_in[12];   // [5,300,600]
    const float* b1  = (const float*)d_in[13];   // [5,600]
    const float* w2  = (const float*)d_in[14];   // [5,600,300]
    const float* b2  = (const float*)d_in[15];   // [5,300]
    const float* gam = (const float*)d_in[16];
    const float* bet = (const float*)d_in[17];
    const float* pw  = (const float*)d_in[18];   // [300,300]
    const float* pb  = (const float*)d_in[19];
    float* out = (float*)d_out;

    // ---- workspace ----
    char* wsb = (char*)d_ws;
    bf16* h    = (bf16*)(wsb);
    bf16* agg  = (bf16*)(wsb + 60000000);
    bf16* hid  = (bf16*)(wsb + 124000000);
    float* f0  = (float*)(wsb + 244000000);
    float* f1  = (float*)(wsb + 248915200);

    // ---- d_out scratch (consumed before logits GEMM) ----
    int* deg      = (int*)d_out;              // N+1
    int* rowstart = deg + (N + 1);            // N+1
    int* cursor   = rowstart + (N + 1);       // N
    int* esorted  = cursor + N;               // E
    int* csum     = esorted + E;              // 512
    int* coff     = csum + 512;               // 512
    int* gstart   = coff + 512;               // 4097
    float* stats  = (float*)(gstart + 4097);  // 600
    char* splits  = (char*)d_out + 2824192;   // 256B-aligned
    unsigned short* w1hi = (unsigned short*)(splits);               // 5*[640][320]
    unsigned short* w1lo = (unsigned short*)(splits + 2048000);
    unsigned short* w2hi = (unsigned short*)(splits + 4096000);     // 5*[384][640]
    unsigned short* w2lo = (unsigned short*)(splits + 6553600);
    unsigned short* pjhi = (unsigned short*)(splits + 9011200);     // [384][320]
    unsigned short* pjlo = (unsigned short*)(splits + 9256960);

    const int TB = 256;
    const int nh_blocks = ceil_div(N * EMBC, TB);
    const int na_blocks = ceil_div(N * AGGC, TB);
    const int nchunks = ceil_div(N + 1, 256);
    const int chunk = ceil_div(N, 256);
    const float invN = 1.f / (float)N;

    // ---- split all weights (once; shared by both branches) ----
    for (int l = 0; l < 5; ++l) {
        k_split<<<ceil_div(640 * 320, TB), TB, 0, stream>>>(
            w1 + (size_t)l * EMB * HID, EMB, HID, 320, 640,
            w1hi + (size_t)l * 640 * 320, w1lo + (size_t)l * 640 * 320);
        k_split<<<ceil_div(384 * 640, TB), TB, 0, stream>>>(
            w2 + (size_t)l * HID * EMB, HID, EMB, 640, 384,
            w2hi + (size_t)l * 384 * 640, w2lo + (size_t)l * 384 * 640);
    }
    k_split<<<ceil_div(384 * 320, TB), TB, 0, stream>>>(pw, EMB, EMB, 320, 384, pjhi, pjlo);

    const int mrows = ceil_div(N, GBM);       // 782
    dim3 g1(5, mrows);    // GEMM1: Npad=640 -> 5 col tiles
    dim3 g2(3, mrows);    // GEMM2/proj: Npad=384 -> 3 col tiles
    dim3 gl(ceil_div(NGRAPH, BN), ceil_div(NGRAPH, BM));

    for (int br = 0; br < 2; ++br) {
        float* fout = br == 0 ? f0 : f1;
        // ---- CSR build ----
        k_zero_i<<<ceil_div(N + 1, TB), TB, 0, stream>>>(deg, N + 1);
        k_hist<<<ceil_div(E, TB), TB, 0, stream>>>(ei[br], deg, E);
        k_chunksum<<<nchunks, 256, 0, stream>>>(deg, csum, N + 1);
        k_scanchunks<<<1, 64, 0, stream>>>(csum, coff, nchunks);
        k_scan2<<<nchunks, 256, 0, stream>>>(deg, coff, rowstart, N + 1);
        k_initcursor<<<ceil_div(N, TB), TB, 0, stream>>>(rowstart, cursor, N);
        k_fill<<<ceil_div(E, TB), TB, 0, stream>>>(ei[br], cursor, esorted, E);
        k_gstart<<<ceil_div(NGRAPH + 1, TB), TB, 0, stream>>>(bt[br], gstart, N);
        // ---- encoder ----
        k_init_h<<<nh_blocks, TB, 0, stream>>>(x[br], (const float4*)atom1,
                                               (const float4*)atom2, (bf4*)h, N);
        for (int l = 0; l < 5; ++l) {
            const float* e1 = ee1 + (size_t)l * 6 * EMB;
            const float* e2 = ee2 + (size_t)l * 3 * EMB;
            k_aggregate<<<na_blocks, TB, 0, stream>>>((const bf4*)h, ei[br], ea[br],
                                                      (const float4*)e1, (const float4*)e2,
                                                      rowstart, esorted, stats, l > 0,
                                                      (bf4*)agg, N, E);
            // GEMM1: [N,320] @ [640,320]^T -> hid [N,600]; fully async (agg K-padded)
            k_gemm_mfma<<<g1, 256, 0, stream>>>(
                (const unsigned short*)agg, AGGP, AGGP, AGGP, AGGP,
                w1hi + (size_t)l * 640 * 320, w1lo + (size_t)l * 640 * 320, 320,
                b1 + (size_t)l * HID, (unsigned short*)hid, HID, N, HID, 1);
            // GEMM2: [N,600] @ [384,640]^T -> h [N,300]; async 0..575, manual tail
            k_gemm_mfma<<<g2, 256, 0, stream>>>(
                (const unsigned short*)hid, HID, HID, 640, 576,
                w2hi + (size_t)l * 384 * 640, w2lo + (size_t)l * 384 * 640, 640,
                b2 + (size_t)l * EMB, (unsigned short*)h, EMB, N, EMB, 0);
            k_zero_f<<<ceil_div(2 * EMB, TB), TB, 0, stream>>>(stats, 2 * EMB);
            k_colstats<<<256, 320, 0, stream>>>(h, stats, N, chunk);
            k_bn_prep<<<1, 320, 0, stream>>>(stats, gam + (size_t)l * EMB,
                                             bet + (size_t)l * EMB, invN);
        }
        // BN(h) copy (pitch 320, zero-padded) into hid buffer for projector
        k_bncopy<<<na_blocks, TB, 0, stream>>>((const bf4*)h, stats, (bf4*)hid, N);
        // projector: [N,320] @ [384,320]^T -> agg (pitch 320); fully async
        k_gemm_mfma<<<g2, 256, 0, stream>>>(
            (const unsigned short*)hid, AGGP, AGGP, AGGP, AGGP,
            pjhi, pjlo, 320, pb, (unsigned short*)agg, AGGP, N, EMB, 0);
        // fused pool + mean + L2 norm
        k_poolnorm<<<NGRAPH, 320, 0, stream>>>(agg, gstart, fout);
    }
    // logits = f0 @ f1^T / TEMP (overwrites d_out scratch)
    k_gemm_nt<<<gl, 256, 0, stream>>>(f0, f1, out, NGRAPH, NGRAPH, EMB, INV_TEMP);
}

// Round 5
// 4461.709 us; speedup vs baseline: 4.0275x; 1.3211x over previous
//
#include <hip/hip_runtime.h>
#include <hip/hip_bf16.h>

// 5-layer GNN encoder x2 branches + projector + mean-pool + L2norm + logits.
// Round 5: (a) logits GEMM on MFMA with hi/lo split of both operands (3-pass,
// fp32-equivalent); (b) aggregate uses packed src|combo + 18-combo embedding
// table (1 broadcast load + 1 coalesced gather per edge-chunk); (c) BN column
// stats fused into GEMM2 epilogue (fp32 pre-rounding values, colstats kernel
// removed). GEMM main loop unchanged from round 4 (m97-style async staging).
//
// d_ws layout (bytes), total 253,830,400:
//   h    bf16 [N,300]  @ 0            pre-BN layer output
//   agg  bf16 [N,320]  @ 60,000,000   K-padded zeros in 300..319
//   hid  bf16 [N,600]  @ 124,000,000  (reused: BN(h) copy; then f-splits for logits)
//   f0   f32  [4096,300] @ 244,000,000
//   f1   f32  [4096,300] @ 248,915,200
// d_out doubles as scratch (CSR + packed + stats + combo table + split weights
// ~14MB), all consumed before the final logits GEMM overwrites it.

#define EMB 300
#define EMBC 75       // 300/4 chunks (h pitch 300)
#define AGGP 320      // agg row pitch (elems)
#define AGGC 80
#define HID 600
#define NGRAPH 4096
#define BN_EPS 1e-5f
#define INV_TEMP 25.0f

typedef __hip_bfloat16 bf16;
struct __align__(8) bf4 { bf16 x, y, z, w; };
typedef __attribute__((ext_vector_type(8))) short short8;
typedef __attribute__((ext_vector_type(4))) float float4v;

__device__ inline float b2f(bf16 v) { return __bfloat162float(v); }
__device__ inline bf16 f2b(float v) { return __float2bfloat16(v); }
__device__ inline unsigned short f2bu(float f) {
    bf16 b = __float2bfloat16(f); unsigned short u; __builtin_memcpy(&u, &b, 2); return u;
}

// async global->LDS, 16 bytes per lane; LDS dest = uniform base + lane*16
typedef const unsigned int __attribute__((address_space(1)))* gas_t;
typedef unsigned int __attribute__((address_space(3)))* las_t;
__device__ __forceinline__ void gl_lds16(const unsigned short* g, unsigned short* l) {
    __builtin_amdgcn_global_load_lds((gas_t)g, (las_t)l, 16, 0, 0);
}

// ---------------- small utility ----------------

__global__ void k_zero_f(float* __restrict__ p, int n) {
    int i = blockIdx.x * blockDim.x + threadIdx.x;
    if (i < n) p[i] = 0.f;
}
__global__ void k_zero_i(int* __restrict__ p, int n) {
    int i = blockIdx.x * blockDim.x + threadIdx.x;
    if (i < n) p[i] = 0;
}

// ---------------- weight split: W[K][N] f32 -> Wt_hi/lo[Npad][Kpad] bf16 ----------------

__global__ void k_split(const float* __restrict__ W, int K, int N, int Kpad, int Npad,
                        unsigned short* __restrict__ hi, unsigned short* __restrict__ lo) {
    int idx = blockIdx.x * blockDim.x + threadIdx.x;
    if (idx >= Npad * Kpad) return;
    int n = idx / Kpad, k = idx % Kpad;
    float v = (n < N && k < K) ? W[(size_t)k * N + n] : 0.f;
    bf16 h = __float2bfloat16(v);
    float rem = v - __bfloat162float(h);
    bf16 l = __float2bfloat16(rem);
    unsigned short hu, lu;
    __builtin_memcpy(&hu, &h, 2); __builtin_memcpy(&lu, &l, 2);
    hi[idx] = hu; lo[idx] = lu;
}

// f[G,300] f32 -> hi/lo [G,320] bf16 (pad zero)
__global__ void k_fsplit(const float* __restrict__ f, unsigned short* __restrict__ hi,
                         unsigned short* __restrict__ lo, int G) {
    int idx = blockIdx.x * blockDim.x + threadIdx.x;
    if (idx >= G * AGGP) return;
    int g = idx / AGGP, c = idx % AGGP;
    float v = (c < EMB) ? f[(size_t)g * EMB + c] : 0.f;
    bf16 h = __float2bfloat16(v);
    float rem = v - __bfloat162float(h);
    hi[idx] = f2bu(v) , hi[idx] = 0;  // placeholder overwritten below
    unsigned short hu; __builtin_memcpy(&hu, &h, 2);
    hi[idx] = hu;
    lo[idx] = f2bu(rem);
}

// ---------------- CSR build (dst-sorted edge ids) ----------------

__global__ void k_hist(const int* __restrict__ ei, int* __restrict__ deg, int E) {
    int e = blockIdx.x * blockDim.x + threadIdx.x;
    if (e < E) atomicAdd(&deg[ei[E + e]], 1);
}

__global__ void k_chunksum(const int* __restrict__ deg, int* __restrict__ csum, int total) {
    __shared__ int s[256];
    int t = threadIdx.x, i = blockIdx.x * 256 + t;
    s[t] = (i < total) ? deg[i] : 0;
    __syncthreads();
    for (int off = 128; off > 0; off >>= 1) {
        if (t < off) s[t] += s[t + off];
        __syncthreads();
    }
    if (t == 0) csum[blockIdx.x] = s[0];
}

__global__ void k_scanchunks(const int* __restrict__ csum, int* __restrict__ coff, int n) {
    if (threadIdx.x == 0) {
        int acc = 0;
        for (int b = 0; b < n; ++b) { coff[b] = acc; acc += csum[b]; }
    }
}

__global__ void k_scan2(const int* __restrict__ deg, const int* __restrict__ coff,
                        int* __restrict__ rowstart, int total) {
    __shared__ int s[256];
    int t = threadIdx.x, b = blockIdx.x, i = b * 256 + t;
    int v = (i < total) ? deg[i] : 0;
    s[t] = v;
    __syncthreads();
    for (int off = 1; off < 256; off <<= 1) {
        int u = (t >= off) ? s[t - off] : 0;
        __syncthreads();
        s[t] += u;
        __syncthreads();
    }
    if (i < total) rowstart[i] = coff[b] + s[t] - v;
}

__global__ void k_initcursor(const int* __restrict__ rowstart, int* __restrict__ cur, int N) {
    int i = blockIdx.x * blockDim.x + threadIdx.x;
    if (i < N) cur[i] = rowstart[i];
}

__global__ void k_fill(const int* __restrict__ ei, int* __restrict__ cur,
                       int* __restrict__ esorted, int E) {
    int e = blockIdx.x * blockDim.x + threadIdx.x;
    if (e < E) {
        int p = atomicAdd(&cur[ei[E + e]], 1);
        esorted[p] = e;
    }
}

// packed[p] = src | (combo<<17), combo = a0*3+a1 (18 combos; self-loop=12)
__global__ void k_pack(const int* __restrict__ ei, const int* __restrict__ ea,
                       const int* __restrict__ esorted, int* __restrict__ packed, int E) {
    int p = blockIdx.x * blockDim.x + threadIdx.x;
    if (p >= E) return;
    int e = esorted[p];
    int s = ei[e];
    int cb = ea[2 * e] * 3 + ea[2 * e + 1];
    packed[p] = s | (cb << 17);
}

__global__ void k_gstart(const int* __restrict__ batch, int* __restrict__ gstart, int N) {
    int g = blockIdx.x * blockDim.x + threadIdx.x;
    if (g > NGRAPH) return;
    int lo = 0, hi = N;
    while (lo < hi) { int mid = (lo + hi) >> 1; if (batch[mid] < g) lo = mid + 1; else hi = mid; }
    gstart[g] = lo;
}

// per-layer combo table: cmb[cb][300] = e1[cb/3] + e2[cb%3]  (fp32)
__global__ void k_combo(const float4* __restrict__ e1, const float4* __restrict__ e2,
                        float4* __restrict__ cmb) {
    int t = blockIdx.x * blockDim.x + threadIdx.x;
    if (t >= 18 * EMBC) return;
    int cb = t / EMBC, j = t % EMBC;
    float4 u = e1[(cb / 3) * EMBC + j];
    float4 v = e2[(cb % 3) * EMBC + j];
    float4 r; r.x = u.x + v.x; r.y = u.y + v.y; r.z = u.z + v.z; r.w = u.w + v.w;
    cmb[t] = r;
}

// ---------------- node init & aggregation (with fused BN affine) ----------------

__global__ void k_init_h(const int* __restrict__ x,
                         const float4* __restrict__ ae1,
                         const float4* __restrict__ ae2,
                         bf4* __restrict__ h4, int N) {
    int idx = blockIdx.x * blockDim.x + threadIdx.x;
    if (idx >= N * EMBC) return;
    int i = idx / EMBC, j = idx % EMBC;
    int a0 = x[2 * i], a1 = x[2 * i + 1];
    float4 u = ae1[a0 * EMBC + j];
    float4 v = ae2[a1 * EMBC + j];
    bf4 r = { f2b(u.x + v.x), f2b(u.y + v.y), f2b(u.z + v.z), f2b(u.w + v.w) };
    h4[idx] = r;
}

// agg[n] = act(h[n]) + cmb[12] + sum_p ( act(h[src(p)]) + cmb[combo(p)] )
// act(x) = relu(scale*x + shift) when use_aff, else x. Pitch AGGP, pad zeroed.
__global__ void k_aggregate(const bf4* __restrict__ h4,
                            const int* __restrict__ packed,
                            const float4* __restrict__ cmb,   // [18,75]
                            const int* __restrict__ rowstart,
                            const float* __restrict__ stats, int use_aff,
                            bf4* __restrict__ agg4, int N) {
    int idx = blockIdx.x * blockDim.x + threadIdx.x;
    if (idx >= N * AGGC) return;
    int n = idx / AGGC, j = idx % AGGC;
    if (j >= EMBC) {
        bf4 z = { f2b(0.f), f2b(0.f), f2b(0.f), f2b(0.f) };
        agg4[idx] = z;
        return;
    }
    float4 sc = make_float4(1.f, 1.f, 1.f, 1.f);
    float4 sh = make_float4(0.f, 0.f, 0.f, 0.f);
    if (use_aff) {
        sc = ((const float4*)stats)[j];
        sh = ((const float4*)(stats + EMB))[j];
    }
    bf4 hv = h4[(size_t)n * EMBC + j];
    float hx = b2f(hv.x), hy = b2f(hv.y), hz = b2f(hv.z), hw = b2f(hv.w);
    if (use_aff) {
        hx = fmaxf(hx * sc.x + sh.x, 0.f); hy = fmaxf(hy * sc.y + sh.y, 0.f);
        hz = fmaxf(hz * sc.z + sh.z, 0.f); hw = fmaxf(hw * sc.w + sh.w, 0.f);
    }
    float4 s0 = cmb[12 * EMBC + j];      // self-loop combo (edge_attr [4,0])
    float ax = hx + s0.x, ay = hy + s0.y, az = hz + s0.z, aw = hw + s0.w;
    int p0 = rowstart[n], p1 = rowstart[n + 1];
    for (int p = p0; p < p1; ++p) {
        int u = packed[p];
        int s = u & 131071;
        int cb = u >> 17;
        bf4 hs = h4[(size_t)s * EMBC + j];
        float gx = b2f(hs.x), gy = b2f(hs.y), gz = b2f(hs.z), gw = b2f(hs.w);
        if (use_aff) {
            gx = fmaxf(gx * sc.x + sh.x, 0.f); gy = fmaxf(gy * sc.y + sh.y, 0.f);
            gz = fmaxf(gz * sc.z + sh.z, 0.f); gw = fmaxf(gw * sc.w + sh.w, 0.f);
        }
        float4 cv = cmb[cb * EMBC + j];
        ax += gx + cv.x; ay += gy + cv.y;
        az += gz + cv.z; aw += gw + cv.w;
    }
    bf4 r = { f2b(ax), f2b(ay), f2b(az), f2b(aw) };
    agg4[idx] = r;
}

// BN(h) copy for projector: dst[N,320] = scale*h + shift (no relu), pad zeroed
__global__ void k_bncopy(const bf4* __restrict__ h4, const float* __restrict__ stats,
                         bf4* __restrict__ dst, int N) {
    int idx = blockIdx.x * blockDim.x + threadIdx.x;
    if (idx >= N * AGGC) return;
    int n = idx / AGGC, j = idx % AGGC;
    if (j >= EMBC) {
        bf4 z = { f2b(0.f), f2b(0.f), f2b(0.f), f2b(0.f) };
        dst[idx] = z;
        return;
    }
    float4 sc = ((const float4*)stats)[j];
    float4 sh = ((const float4*)(stats + EMB))[j];
    bf4 v = h4[(size_t)n * EMBC + j];
    bf4 r = { f2b(b2f(v.x) * sc.x + sh.x), f2b(b2f(v.y) * sc.y + sh.y),
              f2b(b2f(v.z) * sc.z + sh.z), f2b(b2f(v.w) * sc.w + sh.w) };
    dst[idx] = r;
}

// ---------------- MFMA GEMM: C_bf16[M,Nc] = A_bf16[M,K] @ (Bhi+Blo)^T + bias --------
// Tile 128x128x64, async staging, XOR swizzle (round 4, verified). Optional
// fused BN column stats (sum/sumsq of fp32 pre-rounding C) via LDS reduce.

#define GBM 128
#define GBN 128
#define GBK 64

__global__ __launch_bounds__(256)
void k_gemm_mfma(const unsigned short* __restrict__ A, int lda, int Kreal,
                 int Kpad, int Kasync,
                 const unsigned short* __restrict__ Bhi,
                 const unsigned short* __restrict__ Blo, int ldb,
                 const float* __restrict__ bias,
                 unsigned short* __restrict__ C, int ldc, int M, int Nc, int relu,
                 float* __restrict__ stats, int do_stats) {
    __shared__ unsigned short As[GBM][GBK];   // 16 KB (reused as cred in epilogue)
    __shared__ unsigned short Bh[GBN][GBK];   // 16 KB
    __shared__ unsigned short Bl[GBN][GBK];   // 16 KB

    int tid = threadIdx.x;
    int wv = tid >> 6, lane = tid & 63;
    int quad = lane >> 4, l16 = lane & 15;
    int lrow = lane >> 3;
    int gchunk = (lane & 7) ^ lrow;
    int sw = lane & 7;
    int row0 = blockIdx.y * GBM;
    int col0 = blockIdx.x * GBN;

    float4v acc[2][8];
    #pragma unroll
    for (int i = 0; i < 2; ++i)
        #pragma unroll
        for (int j = 0; j < 8; ++j) acc[i][j] = (float4v){0.f, 0.f, 0.f, 0.f};

    for (int k0 = 0; k0 < Kpad; k0 += GBK) {
        if (k0 < Kasync) {
            #pragma unroll
            for (int j = 0; j < 4; ++j) {
                int r = 32 * wv + 8 * j + lrow;
                int gr = min(row0 + r, M - 1);
                gl_lds16(A + (size_t)gr * lda + k0 + gchunk * 8, &As[32 * wv + 8 * j][0]);
            }
            #pragma unroll
            for (int j = 0; j < 4; ++j) {
                int r = 32 * wv + 8 * j + lrow;
                size_t go = (size_t)(col0 + r) * ldb + k0 + gchunk * 8;
                gl_lds16(Bhi + go, &Bh[32 * wv + 8 * j][0]);
                gl_lds16(Blo + go, &Bl[32 * wv + 8 * j][0]);
            }
        } else {
            #pragma unroll
            for (int i = 0; i < 4; ++i) {
                int cidx = tid + i * 256;
                int r = cidx >> 3, s = cidx & 7;
                int g = s ^ (r & 7);
                int gr = min(row0 + r, M - 1);
                unsigned short tmp[8];
                #pragma unroll
                for (int t = 0; t < 8; ++t) {
                    int gk = k0 + g * 8 + t;
                    tmp[t] = (gk < Kreal) ? A[(size_t)gr * lda + gk] : (unsigned short)0;
                }
                uint4 w; __builtin_memcpy(&w, tmp, 16);
                *(uint4*)(&As[r][s * 8]) = w;
            }
            #pragma unroll
            for (int j = 0; j < 4; ++j) {
                int r = 32 * wv + 8 * j + lrow;
                size_t go = (size_t)(col0 + r) * ldb + k0 + gchunk * 8;
                gl_lds16(Bhi + go, &Bh[32 * wv + 8 * j][0]);
                gl_lds16(Blo + go, &Bl[32 * wv + 8 * j][0]);
            }
        }
        __syncthreads();

        int mbase = wv * 32;
        #pragma unroll
        for (int ks = 0; ks < GBK; ks += 32) {
            int lc = (ks >> 3) + quad;
            int pc = lc ^ sw;
            short8 a0 = *(const short8*)(&As[mbase + l16][pc * 8]);
            short8 a1 = *(const short8*)(&As[mbase + 16 + l16][pc * 8]);
            #pragma unroll
            for (int nt = 0; nt < 8; ++nt) {
                short8 bh = *(const short8*)(&Bh[nt * 16 + l16][pc * 8]);
                short8 bl = *(const short8*)(&Bl[nt * 16 + l16][pc * 8]);
                acc[0][nt] = __builtin_amdgcn_mfma_f32_16x16x32_bf16(a0, bh, acc[0][nt], 0, 0, 0);
                acc[0][nt] = __builtin_amdgcn_mfma_f32_16x16x32_bf16(a0, bl, acc[0][nt], 0, 0, 0);
                acc[1][nt] = __builtin_amdgcn_mfma_f32_16x16x32_bf16(a1, bh, acc[1][nt], 0, 0, 0);
                acc[1][nt] = __builtin_amdgcn_mfma_f32_16x16x32_bf16(a1, bl, acc[1][nt], 0, 0, 0);
            }
        }
        __syncthreads();
    }

    // epilogue: C/D layout col=lane&15, row=quad*4+reg
    float sv[8], qv[8];
    #pragma unroll
    for (int nt = 0; nt < 8; ++nt) { sv[nt] = 0.f; qv[nt] = 0.f; }
    #pragma unroll
    for (int mt = 0; mt < 2; ++mt) {
        int rbase = row0 + wv * 32 + mt * 16 + quad * 4;
        #pragma unroll
        for (int nt = 0; nt < 8; ++nt) {
            int c = col0 + nt * 16 + l16;
            if (c >= Nc) continue;
            float bs = bias[c];
            #pragma unroll
            for (int i = 0; i < 4; ++i) {
                int r = rbase + i;
                if (r >= M) continue;
                float v = acc[mt][nt][i] + bs;
                if (relu) v = fmaxf(v, 0.f);
                if (do_stats) { sv[nt] += v; qv[nt] += v * v; }
                C[(size_t)r * ldc + c] = f2bu(v);
            }
        }
    }
    if (do_stats) {
        float* cred = (float*)(&As[0][0]);   // 8*128 floats, aliases As (free now)
        #pragma unroll
        for (int nt = 0; nt < 8; ++nt) {
            float s = sv[nt], q = qv[nt];
            s += __shfl_down(s, 32, 64); s += __shfl_down(s, 16, 64);
            q += __shfl_down(q, 32, 64); q += __shfl_down(q, 16, 64);
            if (quad == 0) {
                cred[(wv * 2 + 0) * 128 + nt * 16 + l16] = s;
                cred[(wv * 2 + 1) * 128 + nt * 16 + l16] = q;
            }
        }
        __syncthreads();
        if (tid < 128) {
            int c = col0 + tid;
            if (c < Nc) {
                float s = cred[0 * 128 + tid] + cred[2 * 128 + tid] +
                          cred[4 * 128 + tid] + cred[6 * 128 + tid];
                float q = cred[1 * 128 + tid] + cred[3 * 128 + tid] +
                          cred[5 * 128 + tid] + cred[7 * 128 + tid];
                atomicAdd(&stats[c], s);
                atomicAdd(&stats[EMB + c], q);
            }
        }
    }
}

// ---------------- logits MFMA: out = scale * (Ah+Al) @ (Bh+Bl)^T  (ll skipped) ----
// A,B: [4096,320] bf16 hi/lo, zero-padded. Tile 64x128x64. No guards (exact).

__global__ __launch_bounds__(256)
void k_logits(const unsigned short* __restrict__ Ahg, const unsigned short* __restrict__ Alg,
              const unsigned short* __restrict__ Bhg, const unsigned short* __restrict__ Blg,
              float* __restrict__ C, float scale) {
    __shared__ unsigned short sAh[64][64];    // 8 KB
    __shared__ unsigned short sAl[64][64];    // 8 KB
    __shared__ unsigned short sBh[128][64];   // 16 KB
    __shared__ unsigned short sBl[128][64];   // 16 KB

    int tid = threadIdx.x;
    int wv = tid >> 6, lane = tid & 63;
    int quad = lane >> 4, l16 = lane & 15;
    int lrow = lane >> 3;
    int gchunk = (lane & 7) ^ lrow;
    int sw = lane & 7;
    int row0 = blockIdx.y * 64;
    int col0 = blockIdx.x * 128;

    float4v acc[8];
    #pragma unroll
    for (int j = 0; j < 8; ++j) acc[j] = (float4v){0.f, 0.f, 0.f, 0.f};

    for (int k0 = 0; k0 < AGGP; k0 += 64) {
        #pragma unroll
        for (int j = 0; j < 2; ++j) {
            int r = 16 * wv + 8 * j + lrow;
            size_t go = (size_t)(row0 + r) * AGGP + k0 + gchunk * 8;
            gl_lds16(Ahg + go, &sAh[16 * wv + 8 * j][0]);
            gl_lds16(Alg + go, &sAl[16 * wv + 8 * j][0]);
        }
        #pragma unroll
        for (int j = 0; j < 4; ++j) {
            int r = 32 * wv + 8 * j + lrow;
            size_t go = (size_t)(col0 + r) * AGGP + k0 + gchunk * 8;
            gl_lds16(Bhg + go, &sBh[32 * wv + 8 * j][0]);
            gl_lds16(Blg + go, &sBl[32 * wv + 8 * j][0]);
        }
        __syncthreads();

        #pragma unroll
        for (int ks = 0; ks < 64; ks += 32) {
            int pc = ((ks >> 3) + quad) ^ sw;
            short8 ah = *(const short8*)(&sAh[wv * 16 + l16][pc * 8]);
            short8 al = *(const short8*)(&sAl[wv * 16 + l16][pc * 8]);
            #pragma unroll
            for (int nt = 0; nt < 8; ++nt) {
                short8 bh = *(const short8*)(&sBh[nt * 16 + l16][pc * 8]);
                short8 bl = *(const short8*)(&sBl[nt * 16 + l16][pc * 8]);
                acc[nt] = __builtin_amdgcn_mfma_f32_16x16x32_bf16(ah, bh, acc[nt], 0, 0, 0);
                acc[nt] = __builtin_amdgcn_mfma_f32_16x16x32_bf16(ah, bl, acc[nt], 0, 0, 0);
                acc[nt] = __builtin_amdgcn_mfma_f32_16x16x32_bf16(al, bh, acc[nt], 0, 0, 0);
            }
        }
        __syncthreads();
    }

    int rbase = row0 + wv * 16 + quad * 4;
    #pragma unroll
    for (int nt = 0; nt < 8; ++nt) {
        int c = col0 + nt * 16 + l16;
        #pragma unroll
        for (int i = 0; i < 4; ++i)
            C[(size_t)(rbase + i) * NGRAPH + c] = acc[nt][i] * scale;
    }
}

// ---------------- BN prep ----------------

__global__ void k_bn_prep(float* __restrict__ stats, const float* __restrict__ gamma,
                          const float* __restrict__ beta, float invN) {
    int c = threadIdx.x;
    if (c >= EMB) return;
    float mean = stats[c] * invN;
    float var = stats[EMB + c] * invN - mean * mean;
    float scale = gamma[c] * rsqrtf(var + BN_EPS);
    stats[c] = scale;
    stats[EMB + c] = beta[c] - mean * scale;
}

// ---------------- fused pool + mean + L2 normalize (proj pitch 320) ----------------

__global__ void k_poolnorm(const bf16* __restrict__ proj, const int* __restrict__ gstart,
                           float* __restrict__ f) {
    int g = blockIdx.x, t = threadIdx.x;
    int s = gstart[g], e = gstart[g + 1];
    float sum = 0.f;
    if (t < EMB)
        for (int r = s; r < e; ++r) sum += b2f(proj[(size_t)r * AGGP + t]);
    float cnt = fmaxf((float)(e - s), 1.f);
    float m = sum / cnt;
    float q = (t < EMB) ? m * m : 0.f;
    for (int off = 32; off > 0; off >>= 1) q += __shfl_down(q, off, 64);
    __shared__ float red[5];
    int lane = t & 63, wid = t >> 6;
    if (lane == 0) red[wid] = q;
    __syncthreads();
    float tot = red[0] + red[1] + red[2] + red[3] + red[4];
    float invn = 1.f / fmaxf(sqrtf(tot), 1e-12f);
    if (t < EMB) f[(size_t)g * EMB + t] = m * invn;
}

// ---------------- host ----------------

static inline int ceil_div(int a, int b) { return (a + b - 1) / b; }

extern "C" void kernel_launch(void* const* d_in, const int* in_sizes, int n_in,
                              void* d_out, int out_size, void* d_ws, size_t ws_size,
                              hipStream_t stream) {
    const int N = in_sizes[0] / 2;    // 100000
    const int E = in_sizes[1] / 2;    // 400000

    const int* x[2]  = { (const int*)d_in[0], (const int*)d_in[4] };
    const int* ei[2] = { (const int*)d_in[1], (const int*)d_in[5] };
    const int* ea[2] = { (const int*)d_in[2], (const int*)d_in[6] };
    const int* bt[2] = { (const int*)d_in[3], (const int*)d_in[7] };
    const float* atom1 = (const float*)d_in[8];
    const float* atom2 = (const float*)d_in[9];
    const float* ee1 = (const float*)d_in[10];   // [5,6,300]
    const float* ee2 = (const float*)d_in[11];   // [5,3,300]
    const float* w1  = (const float*)d_in[12];   // [5,300,600]
    const float* b1  = (const float*)d_in[13];   // [5,600]
    const float* w2  = (const float*)d_in[14];   // [5,600,300]
    const float* b2  = (const float*)d_in[15];   // [5,300]
    const float* gam = (const float*)d_in[16];
    const float* bet = (const float*)d_in[17];
    const float* pw  = (const float*)d_in[18];   // [300,300]
    const float* pb  = (const float*)d_in[19];
    float* out = (float*)d_out;

    // ---- workspace ----
    char* wsb = (char*)d_ws;
    bf16* h    = (bf16*)(wsb);
    bf16* agg  = (bf16*)(wsb + 60000000);
    bf16* hid  = (bf16*)(wsb + 124000000);
    float* f0  = (float*)(wsb + 244000000);
    float* f1  = (float*)(wsb + 248915200);
    // f-splits for logits reuse the (dead) hid region
    unsigned short* f0hi = (unsigned short*)(wsb + 124000000);
    unsigned short* f0lo = (unsigned short*)(wsb + 126621440);
    unsigned short* f1hi = (unsigned short*)(wsb + 129242880);
    unsigned short* f1lo = (unsigned short*)(wsb + 131864320);

    // ---- d_out scratch (consumed before logits GEMM) ----
    int* deg      = (int*)d_out;              // N+1
    int* rowstart = deg + (N + 1);            // N+1
    int* cursor   = rowstart + (N + 1);       // N
    int* esorted  = cursor + N;               // E
    int* packed   = esorted + E;              // E
    int* csum     = packed + E;               // 512
    int* coff     = csum + 512;               // 512
    int* gstart   = coff + 512;               // 4097
    float* stats  = (float*)(gstart + 4097);  // 600
    float* cmb    = stats + 600;              // 18*300
    char* splits  = (char*)d_out + 4500224;   // 256B-aligned, after ~4.45MB scratch
    unsigned short* w1hi = (unsigned short*)(splits);               // 5*[640][320]
    unsigned short* w1lo = (unsigned short*)(splits + 2048000);
    unsigned short* w2hi = (unsigned short*)(splits + 4096000);     // 5*[384][640]
    unsigned short* w2lo = (unsigned short*)(splits + 6553600);
    unsigned short* pjhi = (unsigned short*)(splits + 9011200);     // [384][320]
    unsigned short* pjlo = (unsigned short*)(splits + 9256960);

    const int TB = 256;
    const int nh_blocks = ceil_div(N * EMBC, TB);
    const int na_blocks = ceil_div(N * AGGC, TB);
    const int nchunks = ceil_div(N + 1, 256);
    const float invN = 1.f / (float)N;

    // ---- split all weights (once; shared by both branches) ----
    for (int l = 0; l < 5; ++l) {
        k_split<<<ceil_div(640 * 320, TB), TB, 0, stream>>>(
            w1 + (size_t)l * EMB * HID, EMB, HID, 320, 640,
            w1hi + (size_t)l * 640 * 320, w1lo + (size_t)l * 640 * 320);
        k_split<<<ceil_div(384 * 640, TB), TB, 0, stream>>>(
            w2 + (size_t)l * HID * EMB, HID, EMB, 640, 384,
            w2hi + (size_t)l * 384 * 640, w2lo + (size_t)l * 384 * 640);
    }
    k_split<<<ceil_div(384 * 320, TB), TB, 0, stream>>>(pw, EMB, EMB, 320, 384, pjhi, pjlo);

    const int mrows = ceil_div(N, GBM);       // 782
    dim3 g1(5, mrows);    // GEMM1: Npad=640
    dim3 g2(3, mrows);    // GEMM2/proj: Npad=384
    dim3 glg(32, 64);     // logits: 4096/128 cols, 4096/64 rows

    for (int br = 0; br < 2; ++br) {
        float* fout = br == 0 ? f0 : f1;
        // ---- CSR build + packed edges ----
        k_zero_i<<<ceil_div(N + 1, TB), TB, 0, stream>>>(deg, N + 1);
        k_hist<<<ceil_div(E, TB), TB, 0, stream>>>(ei[br], deg, E);
        k_chunksum<<<nchunks, 256, 0, stream>>>(deg, csum, N + 1);
        k_scanchunks<<<1, 64, 0, stream>>>(csum, coff, nchunks);
        k_scan2<<<nchunks, 256, 0, stream>>>(deg, coff, rowstart, N + 1);
        k_initcursor<<<ceil_div(N, TB), TB, 0, stream>>>(rowstart, cursor, N);
        k_fill<<<ceil_div(E, TB), TB, 0, stream>>>(ei[br], cursor, esorted, E);
        k_pack<<<ceil_div(E, TB), TB, 0, stream>>>(ei[br], ea[br], esorted, packed, E);
        k_gstart<<<ceil_div(NGRAPH + 1, TB), TB, 0, stream>>>(bt[br], gstart, N);
        // ---- encoder ----
        k_init_h<<<nh_blocks, TB, 0, stream>>>(x[br], (const float4*)atom1,
                                               (const float4*)atom2, (bf4*)h, N);
        for (int l = 0; l < 5; ++l) {
            k_combo<<<ceil_div(18 * EMBC, TB), TB, 0, stream>>>(
                (const float4*)(ee1 + (size_t)l * 6 * EMB),
                (const float4*)(ee2 + (size_t)l * 3 * EMB), (float4*)cmb);
            k_aggregate<<<na_blocks, TB, 0, stream>>>((const bf4*)h, packed,
                                                      (const float4*)cmb, rowstart,
                                                      stats, l > 0, (bf4*)agg, N);
            // GEMM1: [N,320] @ [640,320]^T -> hid [N,600]
            k_gemm_mfma<<<g1, 256, 0, stream>>>(
                (const unsigned short*)agg, AGGP, AGGP, AGGP, AGGP,
                w1hi + (size_t)l * 640 * 320, w1lo + (size_t)l * 640 * 320, 320,
                b1 + (size_t)l * HID, (unsigned short*)hid, HID, N, HID, 1,
                nullptr, 0);
            // zero stats, then GEMM2 with fused column stats (fp32 pre-rounding)
            k_zero_f<<<ceil_div(2 * EMB, TB), TB, 0, stream>>>(stats, 2 * EMB);
            k_gemm_mfma<<<g2, 256, 0, stream>>>(
                (const unsigned short*)hid, HID, HID, 640, 576,
                w2hi + (size_t)l * 384 * 640, w2lo + (size_t)l * 384 * 640, 640,
                b2 + (size_t)l * EMB, (unsigned short*)h, EMB, N, EMB, 0,
                stats, 1);
            k_bn_prep<<<1, 320, 0, stream>>>(stats, gam + (size_t)l * EMB,
                                             bet + (size_t)l * EMB, invN);
        }
        // BN(h) copy (pitch 320, zero-padded) into hid buffer for projector
        k_bncopy<<<na_blocks, TB, 0, stream>>>((const bf4*)h, stats, (bf4*)hid, N);
        // projector: [N,320] @ [384,320]^T -> agg (pitch 320)
        k_gemm_mfma<<<g2, 256, 0, stream>>>(
            (const unsigned short*)hid, AGGP, AGGP, AGGP, AGGP,
            pjhi, pjlo, 320, pb, (unsigned short*)agg, AGGP, N, EMB, 0,
            nullptr, 0);
        // fused pool + mean + L2 norm
        k_poolnorm<<<NGRAPH, 320, 0, stream>>>(agg, gstart, fout);
    }
    // ---- logits: split f0/f1 (hid region now dead), 3-pass MFMA ----
    k_fsplit<<<ceil_div(NGRAPH * AGGP, TB), TB, 0, stream>>>(f0, f0hi, f0lo, NGRAPH);
    k_fsplit<<<ceil_div(NGRAPH * AGGP, TB), TB, 0, stream>>>(f1, f1hi, f1lo, NGRAPH);
    k_logits<<<glg, 256, 0, stream>>>(f0hi, f0lo, f1hi, f1lo, out, INV_TEMP);
}

// Round 6
// 4208.762 us; speedup vs baseline: 4.2695x; 1.0601x over previous
//
#include <hip/hip_runtime.h>
#include <hip/hip_bf16.h>

// 5-layer GNN encoder x2 branches + projector + mean-pool + L2norm + logits.
// Round 6: GEMM wave remap 32x128 -> 2x2 of 64x64 (halves B LDS re-reads;
// was LDS-BW-bound), XCD block swizzle (same-row col-tiles share an XCD L2),
// GEMM2 fully async via zero-weight K-pad + 256B guard after hid.
// Numerics identical to round 5 (split-weight hi/lo, fused BN stats).
//
// d_ws layout (bytes):
//   h    bf16 [N,300]  @ 0            pre-BN layer output
//   agg  bf16 [N,320]  @ 60,000,000   K-padded zeros in 300..319
//   hid  bf16 [N,600]  @ 124,000,000  (reused: BN(h) copy; then f-splits for logits)
//   guard 256B zero    @ 244,000,000  (protects GEMM2 last-row K-overrun)
//   f0   f32  [4096,300] @ 244,000,256
//   f1   f32  [4096,300] @ 248,915,456   total 253,830,656
// d_out doubles as scratch (CSR + packed + stats + combo + split weights),
// all consumed before the final logits GEMM overwrites it.

#define EMB 300
#define EMBC 75       // 300/4 chunks (h pitch 300)
#define AGGP 320      // agg row pitch (elems)
#define AGGC 80
#define HID 600
#define NGRAPH 4096
#define BN_EPS 1e-5f
#define INV_TEMP 25.0f

typedef __hip_bfloat16 bf16;
struct __align__(8) bf4 { bf16 x, y, z, w; };
typedef __attribute__((ext_vector_type(8))) short short8;
typedef __attribute__((ext_vector_type(4))) float float4v;

__device__ inline float b2f(bf16 v) { return __bfloat162float(v); }
__device__ inline bf16 f2b(float v) { return __float2bfloat16(v); }
__device__ inline unsigned short f2bu(float f) {
    bf16 b = __float2bfloat16(f); unsigned short u; __builtin_memcpy(&u, &b, 2); return u;
}

// async global->LDS, 16 bytes per lane; LDS dest = uniform base + lane*16
typedef const unsigned int __attribute__((address_space(1)))* gas_t;
typedef unsigned int __attribute__((address_space(3)))* las_t;
__device__ __forceinline__ void gl_lds16(const unsigned short* g, unsigned short* l) {
    __builtin_amdgcn_global_load_lds((gas_t)g, (las_t)l, 16, 0, 0);
}

// ---------------- small utility ----------------

__global__ void k_zero_f(float* __restrict__ p, int n) {
    int i = blockIdx.x * blockDim.x + threadIdx.x;
    if (i < n) p[i] = 0.f;
}
__global__ void k_zero_i(int* __restrict__ p, int n) {
    int i = blockIdx.x * blockDim.x + threadIdx.x;
    if (i < n) p[i] = 0;
}

// ---------------- weight split: W[K][N] f32 -> Wt_hi/lo[Npad][Kpad] bf16 ----------------

__global__ void k_split(const float* __restrict__ W, int K, int N, int Kpad, int Npad,
                        unsigned short* __restrict__ hi, unsigned short* __restrict__ lo) {
    int idx = blockIdx.x * blockDim.x + threadIdx.x;
    if (idx >= Npad * Kpad) return;
    int n = idx / Kpad, k = idx % Kpad;
    float v = (n < N && k < K) ? W[(size_t)k * N + n] : 0.f;
    bf16 h = __float2bfloat16(v);
    float rem = v - __bfloat162float(h);
    bf16 l = __float2bfloat16(rem);
    unsigned short hu, lu;
    __builtin_memcpy(&hu, &h, 2); __builtin_memcpy(&lu, &l, 2);
    hi[idx] = hu; lo[idx] = lu;
}

// f[G,300] f32 -> hi/lo [G,320] bf16 (pad zero)
__global__ void k_fsplit(const float* __restrict__ f, unsigned short* __restrict__ hi,
                         unsigned short* __restrict__ lo, int G) {
    int idx = blockIdx.x * blockDim.x + threadIdx.x;
    if (idx >= G * AGGP) return;
    int g = idx / AGGP, c = idx % AGGP;
    float v = (c < EMB) ? f[(size_t)g * EMB + c] : 0.f;
    bf16 h = __float2bfloat16(v);
    float rem = v - __bfloat162float(h);
    unsigned short hu; __builtin_memcpy(&hu, &h, 2);
    hi[idx] = hu;
    lo[idx] = f2bu(rem);
}

// ---------------- CSR build (dst-sorted edge ids) ----------------

__global__ void k_hist(const int* __restrict__ ei, int* __restrict__ deg, int E) {
    int e = blockIdx.x * blockDim.x + threadIdx.x;
    if (e < E) atomicAdd(&deg[ei[E + e]], 1);
}

__global__ void k_chunksum(const int* __restrict__ deg, int* __restrict__ csum, int total) {
    __shared__ int s[256];
    int t = threadIdx.x, i = blockIdx.x * 256 + t;
    s[t] = (i < total) ? deg[i] : 0;
    __syncthreads();
    for (int off = 128; off > 0; off >>= 1) {
        if (t < off) s[t] += s[t + off];
        __syncthreads();
    }
    if (t == 0) csum[blockIdx.x] = s[0];
}

__global__ void k_scanchunks(const int* __restrict__ csum, int* __restrict__ coff, int n) {
    if (threadIdx.x == 0) {
        int acc = 0;
        for (int b = 0; b < n; ++b) { coff[b] = acc; acc += csum[b]; }
    }
}

__global__ void k_scan2(const int* __restrict__ deg, const int* __restrict__ coff,
                        int* __restrict__ rowstart, int total) {
    __shared__ int s[256];
    int t = threadIdx.x, b = blockIdx.x, i = b * 256 + t;
    int v = (i < total) ? deg[i] : 0;
    s[t] = v;
    __syncthreads();
    for (int off = 1; off < 256; off <<= 1) {
        int u = (t >= off) ? s[t - off] : 0;
        __syncthreads();
        s[t] += u;
        __syncthreads();
    }
    if (i < total) rowstart[i] = coff[b] + s[t] - v;
}

__global__ void k_initcursor(const int* __restrict__ rowstart, int* __restrict__ cur, int N) {
    int i = blockIdx.x * blockDim.x + threadIdx.x;
    if (i < N) cur[i] = rowstart[i];
}

__global__ void k_fill(const int* __restrict__ ei, int* __restrict__ cur,
                       int* __restrict__ esorted, int E) {
    int e = blockIdx.x * blockDim.x + threadIdx.x;
    if (e < E) {
        int p = atomicAdd(&cur[ei[E + e]], 1);
        esorted[p] = e;
    }
}

// packed[p] = src | (combo<<17), combo = a0*3+a1 (18 combos; self-loop=12)
__global__ void k_pack(const int* __restrict__ ei, const int* __restrict__ ea,
                       const int* __restrict__ esorted, int* __restrict__ packed, int E) {
    int p = blockIdx.x * blockDim.x + threadIdx.x;
    if (p >= E) return;
    int e = esorted[p];
    int s = ei[e];
    int cb = ea[2 * e] * 3 + ea[2 * e + 1];
    packed[p] = s | (cb << 17);
}

__global__ void k_gstart(const int* __restrict__ batch, int* __restrict__ gstart, int N) {
    int g = blockIdx.x * blockDim.x + threadIdx.x;
    if (g > NGRAPH) return;
    int lo = 0, hi = N;
    while (lo < hi) { int mid = (lo + hi) >> 1; if (batch[mid] < g) lo = mid + 1; else hi = mid; }
    gstart[g] = lo;
}

// per-layer combo table: cmb[cb][300] = e1[cb/3] + e2[cb%3]  (fp32)
__global__ void k_combo(const float4* __restrict__ e1, const float4* __restrict__ e2,
                        float4* __restrict__ cmb) {
    int t = blockIdx.x * blockDim.x + threadIdx.x;
    if (t >= 18 * EMBC) return;
    int cb = t / EMBC, j = t % EMBC;
    float4 u = e1[(cb / 3) * EMBC + j];
    float4 v = e2[(cb % 3) * EMBC + j];
    float4 r; r.x = u.x + v.x; r.y = u.y + v.y; r.z = u.z + v.z; r.w = u.w + v.w;
    cmb[t] = r;
}

// ---------------- node init & aggregation (with fused BN affine) ----------------

__global__ void k_init_h(const int* __restrict__ x,
                         const float4* __restrict__ ae1,
                         const float4* __restrict__ ae2,
                         bf4* __restrict__ h4, int N) {
    int idx = blockIdx.x * blockDim.x + threadIdx.x;
    if (idx >= N * EMBC) return;
    int i = idx / EMBC, j = idx % EMBC;
    int a0 = x[2 * i], a1 = x[2 * i + 1];
    float4 u = ae1[a0 * EMBC + j];
    float4 v = ae2[a1 * EMBC + j];
    bf4 r = { f2b(u.x + v.x), f2b(u.y + v.y), f2b(u.z + v.z), f2b(u.w + v.w) };
    h4[idx] = r;
}

// agg[n] = act(h[n]) + cmb[12] + sum_p ( act(h[src(p)]) + cmb[combo(p)] )
__global__ void k_aggregate(const bf4* __restrict__ h4,
                            const int* __restrict__ packed,
                            const float4* __restrict__ cmb,   // [18,75]
                            const int* __restrict__ rowstart,
                            const float* __restrict__ stats, int use_aff,
                            bf4* __restrict__ agg4, int N) {
    int idx = blockIdx.x * blockDim.x + threadIdx.x;
    if (idx >= N * AGGC) return;
    int n = idx / AGGC, j = idx % AGGC;
    if (j >= EMBC) {
        bf4 z = { f2b(0.f), f2b(0.f), f2b(0.f), f2b(0.f) };
        agg4[idx] = z;
        return;
    }
    float4 sc = make_float4(1.f, 1.f, 1.f, 1.f);
    float4 sh = make_float4(0.f, 0.f, 0.f, 0.f);
    if (use_aff) {
        sc = ((const float4*)stats)[j];
        sh = ((const float4*)(stats + EMB))[j];
    }
    bf4 hv = h4[(size_t)n * EMBC + j];
    float hx = b2f(hv.x), hy = b2f(hv.y), hz = b2f(hv.z), hw = b2f(hv.w);
    if (use_aff) {
        hx = fmaxf(hx * sc.x + sh.x, 0.f); hy = fmaxf(hy * sc.y + sh.y, 0.f);
        hz = fmaxf(hz * sc.z + sh.z, 0.f); hw = fmaxf(hw * sc.w + sh.w, 0.f);
    }
    float4 s0 = cmb[12 * EMBC + j];      // self-loop combo (edge_attr [4,0])
    float ax = hx + s0.x, ay = hy + s0.y, az = hz + s0.z, aw = hw + s0.w;
    int p0 = rowstart[n], p1 = rowstart[n + 1];
    for (int p = p0; p < p1; ++p) {
        int u = packed[p];
        int s = u & 131071;
        int cb = u >> 17;
        bf4 hs = h4[(size_t)s * EMBC + j];
        float gx = b2f(hs.x), gy = b2f(hs.y), gz = b2f(hs.z), gw = b2f(hs.w);
        if (use_aff) {
            gx = fmaxf(gx * sc.x + sh.x, 0.f); gy = fmaxf(gy * sc.y + sh.y, 0.f);
            gz = fmaxf(gz * sc.z + sh.z, 0.f); gw = fmaxf(gw * sc.w + sh.w, 0.f);
        }
        float4 cv = cmb[cb * EMBC + j];
        ax += gx + cv.x; ay += gy + cv.y;
        az += gz + cv.z; aw += gw + cv.w;
    }
    bf4 r = { f2b(ax), f2b(ay), f2b(az), f2b(aw) };
    agg4[idx] = r;
}

// BN(h) copy for projector: dst[N,320] = scale*h + shift (no relu), pad zeroed
__global__ void k_bncopy(const bf4* __restrict__ h4, const float* __restrict__ stats,
                         bf4* __restrict__ dst, int N) {
    int idx = blockIdx.x * blockDim.x + threadIdx.x;
    if (idx >= N * AGGC) return;
    int n = idx / AGGC, j = idx % AGGC;
    if (j >= EMBC) {
        bf4 z = { f2b(0.f), f2b(0.f), f2b(0.f), f2b(0.f) };
        dst[idx] = z;
        return;
    }
    float4 sc = ((const float4*)stats)[j];
    float4 sh = ((const float4*)(stats + EMB))[j];
    bf4 v = h4[(size_t)n * EMBC + j];
    bf4 r = { f2b(b2f(v.x) * sc.x + sh.x), f2b(b2f(v.y) * sc.y + sh.y),
              f2b(b2f(v.z) * sc.z + sh.z), f2b(b2f(v.w) * sc.w + sh.w) };
    dst[idx] = r;
}

// ---------------- MFMA GEMM: C_bf16[M,Nc] = A_bf16[M,K] @ (Bhi+Blo)^T + bias --------
// Tile 128x128x64, async staging, XOR LDS swizzle. Waves in 2x2 grid of
// 64x64 tiles (halves B LDS re-reads vs 32x128 strips). XCD block swizzle:
// col-tiles of one row-block get linear ids equal mod 8 -> same XCD L2.
// Fused BN column stats (fp32 pre-rounding) optional.

#define GBM 128
#define GBN 128
#define GBK 64

__global__ __launch_bounds__(256)
void k_gemm_mfma(const unsigned short* __restrict__ A, int lda, int Kreal,
                 int Kpad, int Kasync,
                 const unsigned short* __restrict__ Bhi,
                 const unsigned short* __restrict__ Blo, int ldb,
                 const float* __restrict__ bias,
                 unsigned short* __restrict__ C, int ldc, int M, int Nc, int relu,
                 float* __restrict__ stats, int do_stats) {
    __shared__ unsigned short As[GBM][GBK];   // 16 KB (reused as cred in epilogue)
    __shared__ unsigned short Bh[GBN][GBK];   // 16 KB
    __shared__ unsigned short Bl[GBN][GBK];   // 16 KB

    int tid = threadIdx.x;
    int wv = tid >> 6, lane = tid & 63;
    int quad = lane >> 4, l16 = lane & 15;
    int wm = wv & 1, wn = wv >> 1;            // 2x2 wave grid
    int lrow = lane >> 3;
    int gchunk = (lane & 7) ^ lrow;
    int sw = lane & 7;

    // XCD swizzle
    int ncols = gridDim.x, nrows = gridDim.y;
    int lin = blockIdx.y * ncols + blockIdx.x;
    int g = lin / (8 * ncols);
    int rem = lin - g * 8 * ncols;
    int rows_in = min(8, nrows - g * 8);
    int colb = rem / rows_in;
    int rowb = g * 8 + (rem - colb * rows_in);
    int row0 = rowb * GBM;
    int col0 = colb * GBN;

    float4v acc[4][4];
    #pragma unroll
    for (int i = 0; i < 4; ++i)
        #pragma unroll
        for (int j = 0; j < 4; ++j) acc[i][j] = (float4v){0.f, 0.f, 0.f, 0.f};

    for (int k0 = 0; k0 < Kpad; k0 += GBK) {
        if (k0 < Kasync) {
            #pragma unroll
            for (int j = 0; j < 4; ++j) {
                int r = 32 * wv + 8 * j + lrow;
                int gr = min(row0 + r, M - 1);
                gl_lds16(A + (size_t)gr * lda + k0 + gchunk * 8, &As[32 * wv + 8 * j][0]);
            }
            #pragma unroll
            for (int j = 0; j < 4; ++j) {
                int r = 32 * wv + 8 * j + lrow;
                size_t go = (size_t)(col0 + r) * ldb + k0 + gchunk * 8;
                gl_lds16(Bhi + go, &Bh[32 * wv + 8 * j][0]);
                gl_lds16(Blo + go, &Bl[32 * wv + 8 * j][0]);
            }
        } else {
            #pragma unroll
            for (int i = 0; i < 4; ++i) {
                int cidx = tid + i * 256;
                int r = cidx >> 3, s = cidx & 7;
                int gg = s ^ (r & 7);
                int gr = min(row0 + r, M - 1);
                unsigned short tmp[8];
                #pragma unroll
                for (int t = 0; t < 8; ++t) {
                    int gk = k0 + gg * 8 + t;
                    tmp[t] = (gk < Kreal) ? A[(size_t)gr * lda + gk] : (unsigned short)0;
                }
                uint4 w; __builtin_memcpy(&w, tmp, 16);
                *(uint4*)(&As[r][s * 8]) = w;
            }
            #pragma unroll
            for (int j = 0; j < 4; ++j) {
                int r = 32 * wv + 8 * j + lrow;
                size_t go = (size_t)(col0 + r) * ldb + k0 + gchunk * 8;
                gl_lds16(Bhi + go, &Bh[32 * wv + 8 * j][0]);
                gl_lds16(Blo + go, &Bl[32 * wv + 8 * j][0]);
            }
        }
        __syncthreads();

        int mbase = wm * 64, nbase = wn * 64;
        #pragma unroll
        for (int ks = 0; ks < GBK; ks += 32) {
            int pc = ((ks >> 3) + quad) ^ sw;
            short8 a[4];
            #pragma unroll
            for (int mt = 0; mt < 4; ++mt)
                a[mt] = *(const short8*)(&As[mbase + mt * 16 + l16][pc * 8]);
            #pragma unroll
            for (int nt = 0; nt < 4; ++nt) {
                short8 bh = *(const short8*)(&Bh[nbase + nt * 16 + l16][pc * 8]);
                short8 bl = *(const short8*)(&Bl[nbase + nt * 16 + l16][pc * 8]);
                #pragma unroll
                for (int mt = 0; mt < 4; ++mt) {
                    acc[mt][nt] = __builtin_amdgcn_mfma_f32_16x16x32_bf16(a[mt], bh, acc[mt][nt], 0, 0, 0);
                    acc[mt][nt] = __builtin_amdgcn_mfma_f32_16x16x32_bf16(a[mt], bl, acc[mt][nt], 0, 0, 0);
                }
            }
        }
        __syncthreads();
    }

    // epilogue: C/D layout col=lane&15, row=quad*4+reg
    float sv[4], qv[4];
    #pragma unroll
    for (int nt = 0; nt < 4; ++nt) { sv[nt] = 0.f; qv[nt] = 0.f; }
    #pragma unroll
    for (int mt = 0; mt < 4; ++mt) {
        int rbase = row0 + wm * 64 + mt * 16 + quad * 4;
        #pragma unroll
        for (int nt = 0; nt < 4; ++nt) {
            int c = col0 + wn * 64 + nt * 16 + l16;
            if (c >= Nc) continue;
            float bs = bias[c];
            #pragma unroll
            for (int i = 0; i < 4; ++i) {
                int r = rbase + i;
                if (r >= M) continue;
                float v = acc[mt][nt][i] + bs;
                if (relu) v = fmaxf(v, 0.f);
                if (do_stats) { sv[nt] += v; qv[nt] += v * v; }
                C[(size_t)r * ldc + c] = f2bu(v);
            }
        }
    }
    if (do_stats) {
        float* cred = (float*)(&As[0][0]);   // 4 waves x (64 s + 64 q) floats
        #pragma unroll
        for (int nt = 0; nt < 4; ++nt) {
            float s = sv[nt], q = qv[nt];
            s += __shfl_down(s, 32, 64); s += __shfl_down(s, 16, 64);
            q += __shfl_down(q, 32, 64); q += __shfl_down(q, 16, 64);
            if (quad == 0) {
                cred[wv * 128 + nt * 16 + l16] = s;
                cred[wv * 128 + 64 + nt * 16 + l16] = q;
            }
        }
        __syncthreads();
        if (tid < 128) {
            int c = col0 + tid;
            if (c < Nc) {
                int cin = tid & 63, wvn = tid >> 6;
                float s = cred[(wvn * 2 + 0) * 128 + cin] + cred[(wvn * 2 + 1) * 128 + cin];
                float q = cred[(wvn * 2 + 0) * 128 + 64 + cin] + cred[(wvn * 2 + 1) * 128 + 64 + cin];
                atomicAdd(&stats[c], s);
                atomicAdd(&stats[EMB + c], q);
            }
        }
    }
}

// ---------------- logits MFMA: out = scale * (Ah+Al) @ (Bh+Bl)^T  (ll skipped) ----

__global__ __launch_bounds__(256)
void k_logits(const unsigned short* __restrict__ Ahg, const unsigned short* __restrict__ Alg,
              const unsigned short* __restrict__ Bhg, const unsigned short* __restrict__ Blg,
              float* __restrict__ C, float scale) {
    __shared__ unsigned short sAh[64][64];
    __shared__ unsigned short sAl[64][64];
    __shared__ unsigned short sBh[128][64];
    __shared__ unsigned short sBl[128][64];

    int tid = threadIdx.x;
    int wv = tid >> 6, lane = tid & 63;
    int quad = lane >> 4, l16 = lane & 15;
    int lrow = lane >> 3;
    int gchunk = (lane & 7) ^ lrow;
    int sw = lane & 7;
    int row0 = blockIdx.y * 64;
    int col0 = blockIdx.x * 128;

    float4v acc[8];
    #pragma unroll
    for (int j = 0; j < 8; ++j) acc[j] = (float4v){0.f, 0.f, 0.f, 0.f};

    for (int k0 = 0; k0 < AGGP; k0 += 64) {
        #pragma unroll
        for (int j = 0; j < 2; ++j) {
            int r = 16 * wv + 8 * j + lrow;
            size_t go = (size_t)(row0 + r) * AGGP + k0 + gchunk * 8;
            gl_lds16(Ahg + go, &sAh[16 * wv + 8 * j][0]);
            gl_lds16(Alg + go, &sAl[16 * wv + 8 * j][0]);
        }
        #pragma unroll
        for (int j = 0; j < 4; ++j) {
            int r = 32 * wv + 8 * j + lrow;
            size_t go = (size_t)(col0 + r) * AGGP + k0 + gchunk * 8;
            gl_lds16(Bhg + go, &sBh[32 * wv + 8 * j][0]);
            gl_lds16(Blg + go, &sBl[32 * wv + 8 * j][0]);
        }
        __syncthreads();

        #pragma unroll
        for (int ks = 0; ks < 64; ks += 32) {
            int pc = ((ks >> 3) + quad) ^ sw;
            short8 ah = *(const short8*)(&sAh[wv * 16 + l16][pc * 8]);
            short8 al = *(const short8*)(&sAl[wv * 16 + l16][pc * 8]);
            #pragma unroll
            for (int nt = 0; nt < 8; ++nt) {
                short8 bh = *(const short8*)(&sBh[nt * 16 + l16][pc * 8]);
                short8 bl = *(const short8*)(&sBl[nt * 16 + l16][pc * 8]);
                acc[nt] = __builtin_amdgcn_mfma_f32_16x16x32_bf16(ah, bh, acc[nt], 0, 0, 0);
                acc[nt] = __builtin_amdgcn_mfma_f32_16x16x32_bf16(ah, bl, acc[nt], 0, 0, 0);
                acc[nt] = __builtin_amdgcn_mfma_f32_16x16x32_bf16(al, bh, acc[nt], 0, 0, 0);
            }
        }
        __syncthreads();
    }

    int rbase = row0 + wv * 16 + quad * 4;
    #pragma unroll
    for (int nt = 0; nt < 8; ++nt) {
        int c = col0 + nt * 16 + l16;
        #pragma unroll
        for (int i = 0; i < 4; ++i)
            C[(size_t)(rbase + i) * NGRAPH + c] = acc[nt][i] * scale;
    }
}

// ---------------- BN prep ----------------

__global__ void k_bn_prep(float* __restrict__ stats, const float* __restrict__ gamma,
                          const float* __restrict__ beta, float invN) {
    int c = threadIdx.x;
    if (c >= EMB) return;
    float mean = stats[c] * invN;
    float var = stats[EMB + c] * invN - mean * mean;
    float scale = gamma[c] * rsqrtf(var + BN_EPS);
    stats[c] = scale;
    stats[EMB + c] = beta[c] - mean * scale;
}

// ---------------- fused pool + mean + L2 normalize (proj pitch 320) ----------------

__global__ void k_poolnorm(const bf16* __restrict__ proj, const int* __restrict__ gstart,
                           float* __restrict__ f) {
    int g = blockIdx.x, t = threadIdx.x;
    int s = gstart[g], e = gstart[g + 1];
    float sum = 0.f;
    if (t < EMB)
        for (int r = s; r < e; ++r) sum += b2f(proj[(size_t)r * AGGP + t]);
    float cnt = fmaxf((float)(e - s), 1.f);
    float m = sum / cnt;
    float q = (t < EMB) ? m * m : 0.f;
    for (int off = 32; off > 0; off >>= 1) q += __shfl_down(q, off, 64);
    __shared__ float red[5];
    int lane = t & 63, wid = t >> 6;
    if (lane == 0) red[wid] = q;
    __syncthreads();
    float tot = red[0] + red[1] + red[2] + red[3] + red[4];
    float invn = 1.f / fmaxf(sqrtf(tot), 1e-12f);
    if (t < EMB) f[(size_t)g * EMB + t] = m * invn;
}

// ---------------- host ----------------

static inline int ceil_div(int a, int b) { return (a + b - 1) / b; }

extern "C" void kernel_launch(void* const* d_in, const int* in_sizes, int n_in,
                              void* d_out, int out_size, void* d_ws, size_t ws_size,
                              hipStream_t stream) {
    const int N = in_sizes[0] / 2;    // 100000
    const int E = in_sizes[1] / 2;    // 400000

    const int* x[2]  = { (const int*)d_in[0], (const int*)d_in[4] };
    const int* ei[2] = { (const int*)d_in[1], (const int*)d_in[5] };
    const int* ea[2] = { (const int*)d_in[2], (const int*)d_in[6] };
    const int* bt[2] = { (const int*)d_in[3], (const int*)d_in[7] };
    const float* atom1 = (const float*)d_in[8];
    const float* atom2 = (const float*)d_in[9];
    const float* ee1 = (const float*)d_in[10];   // [5,6,300]
    const float* ee2 = (const float*)d_in[11];   // [5,3,300]
    const float* w1  = (const float*)d_in[12];   // [5,300,600]
    const float* b1  = (const float*)d_in[13];   // [5,600]
    const float* w2  = (const float*)d_in[14];   // [5,600,300]
    const float* b2  = (const float*)d_in[15];   // [5,300]
    const float* gam = (const float*)d_in[16];
    const float* bet = (const float*)d_in[17];
    const float* pw  = (const float*)d_in[18];   // [300,300]
    const float* pb  = (const float*)d_in[19];
    float* out = (float*)d_out;

    // ---- workspace ----
    char* wsb = (char*)d_ws;
    bf16* h    = (bf16*)(wsb);
    bf16* agg  = (bf16*)(wsb + 60000000);
    bf16* hid  = (bf16*)(wsb + 124000000);
    float* guard = (float*)(wsb + 244000000);    // 64 floats, zeroed
    float* f0  = (float*)(wsb + 244000256);
    float* f1  = (float*)(wsb + 248915456);
    // f-splits for logits reuse the (dead) hid region
    unsigned short* f0hi = (unsigned short*)(wsb + 124000000);
    unsigned short* f0lo = (unsigned short*)(wsb + 126621440);
    unsigned short* f1hi = (unsigned short*)(wsb + 129242880);
    unsigned short* f1lo = (unsigned short*)(wsb + 131864320);

    // ---- d_out scratch (consumed before logits GEMM) ----
    int* deg      = (int*)d_out;              // N+1
    int* rowstart = deg + (N + 1);            // N+1
    int* cursor   = rowstart + (N + 1);       // N
    int* esorted  = cursor + N;               // E
    int* packed   = esorted + E;              // E
    int* csum     = packed + E;               // 512
    int* coff     = csum + 512;               // 512
    int* gstart   = coff + 512;               // 4097
    float* stats  = (float*)(gstart + 4097);  // 600
    float* cmb    = stats + 600;              // 18*300
    char* splits  = (char*)d_out + 4500224;   // 256B-aligned
    unsigned short* w1hi = (unsigned short*)(splits);               // 5*[640][320]
    unsigned short* w1lo = (unsigned short*)(splits + 2048000);
    unsigned short* w2hi = (unsigned short*)(splits + 4096000);     // 5*[384][640]
    unsigned short* w2lo = (unsigned short*)(splits + 6553600);
    unsigned short* pjhi = (unsigned short*)(splits + 9011200);     // [384][320]
    unsigned short* pjlo = (unsigned short*)(splits + 9256960);

    const int TB = 256;
    const int nh_blocks = ceil_div(N * EMBC, TB);
    const int na_blocks = ceil_div(N * AGGC, TB);
    const int nchunks = ceil_div(N + 1, 256);
    const float invN = 1.f / (float)N;

    // zero the guard after hid (GEMM2 last-row async K-overrun lands here)
    k_zero_f<<<1, 64, 0, stream>>>(guard, 64);

    // ---- split all weights (once; shared by both branches) ----
    for (int l = 0; l < 5; ++l) {
        k_split<<<ceil_div(640 * 320, TB), TB, 0, stream>>>(
            w1 + (size_t)l * EMB * HID, EMB, HID, 320, 640,
            w1hi + (size_t)l * 640 * 320, w1lo + (size_t)l * 640 * 320);
        k_split<<<ceil_div(384 * 640, TB), TB, 0, stream>>>(
            w2 + (size_t)l * HID * EMB, HID, EMB, 640, 384,
            w2hi + (size_t)l * 384 * 640, w2lo + (size_t)l * 384 * 640);
    }
    k_split<<<ceil_div(384 * 320, TB), TB, 0, stream>>>(pw, EMB, EMB, 320, 384, pjhi, pjlo);

    const int mrows = ceil_div(N, GBM);       // 782
    dim3 g1(5, mrows);    // GEMM1: Npad=640
    dim3 g2(3, mrows);    // GEMM2/proj: Npad=384
    dim3 glg(32, 64);     // logits

    for (int br = 0; br < 2; ++br) {
        float* fout = br == 0 ? f0 : f1;
        // ---- CSR build + packed edges ----
        k_zero_i<<<ceil_div(N + 1, TB), TB, 0, stream>>>(deg, N + 1);
        k_hist<<<ceil_div(E, TB), TB, 0, stream>>>(ei[br], deg, E);
        k_chunksum<<<nchunks, 256, 0, stream>>>(deg, csum, N + 1);
        k_scanchunks<<<1, 64, 0, stream>>>(csum, coff, nchunks);
        k_scan2<<<nchunks, 256, 0, stream>>>(deg, coff, rowstart, N + 1);
        k_initcursor<<<ceil_div(N, TB), TB, 0, stream>>>(rowstart, cursor, N);
        k_fill<<<ceil_div(E, TB), TB, 0, stream>>>(ei[br], cursor, esorted, E);
        k_pack<<<ceil_div(E, TB), TB, 0, stream>>>(ei[br], ea[br], esorted, packed, E);
        k_gstart<<<ceil_div(NGRAPH + 1, TB), TB, 0, stream>>>(bt[br], gstart, N);
        // ---- encoder ----
        k_init_h<<<nh_blocks, TB, 0, stream>>>(x[br], (const float4*)atom1,
                                               (const float4*)atom2, (bf4*)h, N);
        for (int l = 0; l < 5; ++l) {
            k_combo<<<ceil_div(18 * EMBC, TB), TB, 0, stream>>>(
                (const float4*)(ee1 + (size_t)l * 6 * EMB),
                (const float4*)(ee2 + (size_t)l * 3 * EMB), (float4*)cmb);
            k_aggregate<<<na_blocks, TB, 0, stream>>>((const bf4*)h, packed,
                                                      (const float4*)cmb, rowstart,
                                                      stats, l > 0, (bf4*)agg, N);
            // GEMM1: [N,320] @ [640,320]^T -> hid [N,600]
            k_gemm_mfma<<<g1, 256, 0, stream>>>(
                (const unsigned short*)agg, AGGP, AGGP, AGGP, AGGP,
                w1hi + (size_t)l * 640 * 320, w1lo + (size_t)l * 640 * 320, 320,
                b1 + (size_t)l * HID, (unsigned short*)hid, HID, N, HID, 1,
                nullptr, 0);
            // GEMM2 fully async: K 600..639 reads garbage x zero weights = 0
            k_zero_f<<<ceil_div(2 * EMB, TB), TB, 0, stream>>>(stats, 2 * EMB);
            k_gemm_mfma<<<g2, 256, 0, stream>>>(
                (const unsigned short*)hid, HID, HID, 640, 640,
                w2hi + (size_t)l * 384 * 640, w2lo + (size_t)l * 384 * 640, 640,
                b2 + (size_t)l * EMB, (unsigned short*)h, EMB, N, EMB, 0,
                stats, 1);
            k_bn_prep<<<1, 320, 0, stream>>>(stats, gam + (size_t)l * EMB,
                                             bet + (size_t)l * EMB, invN);
        }
        // BN(h) copy (pitch 320, zero-padded) into hid buffer for projector
        k_bncopy<<<na_blocks, TB, 0, stream>>>((const bf4*)h, stats, (bf4*)hid, N);
        // projector: [N,320] @ [384,320]^T -> agg (pitch 320)
        k_gemm_mfma<<<g2, 256, 0, stream>>>(
            (const unsigned short*)hid, AGGP, AGGP, AGGP, AGGP,
            pjhi, pjlo, 320, pb, (unsigned short*)agg, AGGP, N, EMB, 0,
            nullptr, 0);
        // fused pool + mean + L2 norm
        k_poolnorm<<<NGRAPH, 320, 0, stream>>>(agg, gstart, fout);
    }
    // ---- logits: split f0/f1 (hid region now dead), 3-pass MFMA ----
    k_fsplit<<<ceil_div(NGRAPH * AGGP, TB), TB, 0, stream>>>(f0, f0hi, f0lo, NGRAPH);
    k_fsplit<<<ceil_div(NGRAPH * AGGP, TB), TB, 0, stream>>>(f1, f1hi, f1lo, NGRAPH);
    k_logits<<<glg, 256, 0, stream>>>(f0hi, f0lo, f1hi, f1lo, out, INV_TEMP);
}